// Round 6
// baseline (660.897 us; speedup 1.0000x reference)
//
#include <hip/hip_runtime.h>

#define LRC   0.05f
#define B1C   0.9f
#define B2C   0.999f
#define C1C   0.1f      // float(1 - 0.9)
#define C2C   0.001f    // float(1 - 0.999)
#define EPSC  1e-8f

__device__ __forceinline__ float rlane(float v, int l) {
  return __int_as_float(__builtin_amdgcn_readlane(__float_as_int(v), l));
}

// sum-reduce step within 16-lane row via DPP rotate (VALU pipe, no LDS traffic)
template <int CTRL>
__device__ __forceinline__ float dpp_add(float x) {
  int y = __builtin_amdgcn_update_dpp(0, __float_as_int(x), CTRL, 0xF, 0xF, false);
  return x + __int_as_float(y);
}

// full-wave sum replicated in all lanes — DPP row stages + readlane cross-row.
// NO ds_bpermute anywhere (shfl_xor lowers to the DS pipe; this stays on VALU).
__device__ __forceinline__ float wave_sum_repl(float x) {
  x = dpp_add<0x121>(x);            // row_ror:1
  x = dpp_add<0x122>(x);            // row_ror:2
  x = dpp_add<0x124>(x);            // row_ror:4
  x = dpp_add<0x128>(x);            // row_ror:8  -> every lane holds its row sum
  float t0 = rlane(x, 0), t1 = rlane(x, 16), t2 = rlane(x, 32), t3 = rlane(x, 48);
  return (t0 + t1) + (t2 + t3);
}

// batch of N replicated wave sums, stage-interleaved for ILP
template <int N>
__device__ __forceinline__ void wave_sum_batch(float* a) {
  #pragma unroll
  for (int c = 0; c < N; ++c) a[c] = dpp_add<0x121>(a[c]);
  #pragma unroll
  for (int c = 0; c < N; ++c) a[c] = dpp_add<0x122>(a[c]);
  #pragma unroll
  for (int c = 0; c < N; ++c) a[c] = dpp_add<0x124>(a[c]);
  #pragma unroll
  for (int c = 0; c < N; ++c) a[c] = dpp_add<0x128>(a[c]);
  #pragma unroll
  for (int c = 0; c < N; ++c) {
    float t0 = rlane(a[c], 0), t1 = rlane(a[c], 16);
    float t2 = rlane(a[c], 32), t3 = rlane(a[c], 48);
    a[c] = (t0 + t1) + (t2 + t3);
  }
}

// bias-correction constants: 1/(1-b^t), t=1..8
__constant__ float RC1T[8] = {10.0f, 5.2631578947f, 3.6900369004f, 2.9078220413f,
                              2.4419428585f, 2.1342007905f, 1.9167972515f, 1.7558143540f};
__constant__ float RC2T[8] = {1000.0f, 500.2501251f, 333.6669446f, 250.3753310f,
                              200.4003604f, 167.0837822f, 143.2862774f, 125.4381714f};

// ---------------- K1: encode table for the 64 distinct tokens ----------------
__global__ void enc_kernel(
    const float* __restrict__ embed,
    const float* __restrict__ ff_w1, const float* __restrict__ ff_b1,
    const float* __restrict__ ff_w2, const float* __restrict__ ff_b2,
    const float* __restrict__ ln_g, const float* __restrict__ ln_b,
    const float* __restrict__ scorer_w,
    float* __restrict__ enc, float* __restrict__ sAt, float* __restrict__ sBt)
{
  const int b = blockIdx.x;      // token id
  const int lane = threadIdx.x;  // feature

  float e = embed[b * 64 + lane];
  float acc0 = ff_b1[lane], acc1 = ff_b1[64 + lane];
  #pragma unroll
  for (int j = 0; j < 64; ++j) {
    float ej = rlane(e, j);
    acc0 = fmaf(ej, ff_w1[j * 128 + lane], acc0);
    acc1 = fmaf(ej, ff_w1[j * 128 + 64 + lane], acc1);
  }
  acc0 = fmaxf(acc0, 0.f);
  acc1 = fmaxf(acc1, 0.f);

  float f = ff_b2[lane];
  #pragma unroll
  for (int l = 0; l < 64; ++l) {
    f = fmaf(rlane(acc0, l), ff_w2[l * 64 + lane], f);
    f = fmaf(rlane(acc1, l), ff_w2[(l + 64) * 64 + lane], f);
  }

  float x = e + f;
  float mu = wave_sum_repl(x) * (1.f / 64.f);
  float d = x - mu;
  float var = wave_sum_repl(d * d) * (1.f / 64.f);
  float h = d * (1.f / sqrtf(var + 1e-5f)) * ln_g[lane] + ln_b[lane];
  enc[b * 64 + lane] = h;

  float sa = wave_sum_repl(h * scorer_w[lane]);
  float sb = wave_sum_repl(h * scorer_w[64 + lane]);
  if (lane == 0) { sAt[b] = sa; sBt[b] = sb; }
}

// ---------------- Adam per-param update ----------------
__device__ __forceinline__ void adam1(float& p, float& m, float& v, float g,
                                      float lrrc1, float rc2) {
  m = fmaf(B1C, m, C1C * g);
  v = fmaf(B2C, v, (C2C * g) * g);
  float den = sqrtf(v * rc2) + EPSC;
  p = fmaf(-lrrc1, __fdividef(m, den), p);
}

// ---------------- K2: two waves per sample, hidden units split 12/12 ----------------
// block = 256 (4 waves) = 2 samples. wave = (sample-in-block, half).
// Reductions are pure VALU (DPP + readlane); only LDS use is the 1-barrier
// partial-output exchange per Adam step.
__global__ __launch_bounds__(256, 3) void adam_kernel(
    const int* __restrict__ seqs, const float* __restrict__ enc,
    const float* __restrict__ sAt, const float* __restrict__ sBt,
    const float* __restrict__ scorer_b,
    const float* __restrict__ mlp_w1, const float* __restrict__ mlp_b1,
    const float* __restrict__ mlp_w2, const float* __restrict__ mlp_b2,
    const float* __restrict__ out_w, const float* __restrict__ out_b,
    float* __restrict__ out)
{
  const int wid  = threadIdx.x >> 6;
  const int lane = threadIdx.x & 63;
  const int sblk = wid >> 1;           // sample within block
  const int half = wid & 1;            // which 12 hidden units we own
  const int c0   = half * 12;
  const int sample = blockIdx.x * 2 + sblk;

  __shared__ float xbuf[2][2][2][64];  // [sblk][parity][half][lane]

  int tv = seqs[sample * 32 + (lane & 31)];
  float sbv = scorer_b[0];

  // scores from factored tables (wave-uniform; both halves compute identically)
  float sc[15]; int ta[15], tb[15];
  #pragma unroll
  for (int p = 0; p < 15; ++p) {
    ta[p] = __builtin_amdgcn_readlane(tv, 2 * p);
    tb[p] = __builtin_amdgcn_readlane(tv, 2 * p + 1);
    sc[p] = sAt[ta[p]] + sBt[tb[p]] + sbv;
  }
  int q30 = __builtin_amdgcn_readlane(tv, 30);

  // evict-min on (score, token-id); strict < keeps FIRST min
  float bs[8]; int bka[8], bva[8];
  #pragma unroll
  for (int i = 0; i < 8; ++i) { bs[i] = sc[i]; bka[i] = ta[i]; bva[i] = tb[i]; }
  #pragma unroll
  for (int n = 0; n < 7; ++n) {
    int mi = 0; float ms = bs[0];
    #pragma unroll
    for (int i = 1; i < 8; ++i) {
      if (bs[i] < ms) { mi = i; ms = bs[i]; }
    }
    #pragma unroll
    for (int i = 0; i < 7; ++i) {
      bool sh = i >= mi;
      bs[i]  = sh ? bs[i + 1]  : bs[i];
      bka[i] = sh ? bka[i + 1] : bka[i];
      bva[i] = sh ? bva[i + 1] : bva[i];
    }
    bs[7] = sc[8 + n]; bka[7] = ta[8 + n]; bva[7] = tb[8 + n];
  }

  // own params: lane j holds w1[j][c0+c], w2[c0+c][j]; b1 lane-distributed on own range
  float w1r[12], w2c[12], m1[12], v1[12], m2[12], v2[12];
  #pragma unroll
  for (int c = 0; c < 12; ++c) {
    w1r[c] = mlp_w1[lane * 24 + c0 + c];
    w2c[c] = mlp_w2[(c0 + c) * 64 + lane];
    m1[c] = v1[c] = m2[c] = v2[c] = 0.f;
  }
  float b1o = (lane >= c0 && lane < c0 + 12) ? mlp_b1[lane] : 0.f;
  float b2o = mlp_b2[lane];                      // replicated in both halves
  float mb1 = 0.f, vb1 = 0.f, mb2 = 0.f, vb2 = 0.f;

  float kj = enc[bka[0] * 64 + lane];
  float vj = enc[bva[0] * 64 + lane];

  #pragma unroll 1
  for (int step = 0; step < 8; ++step) {
    // prefetch next step's (k,v) pair
    int nidx = (step < 7) ? step + 1 : 7;
    int kan = bka[0], van = bva[0];
    #pragma unroll
    for (int i = 1; i < 8; ++i)
      if (nidx == i) { kan = bka[i]; van = bva[i]; }
    float kjn = enc[kan * 64 + lane];
    float vjn = enc[van * 64 + lane];

    float lrrc1 = LRC * RC1T[step];
    float rc2 = RC2T[step];

    // layer1 for own 12 units: a[c] = relu(b1[c0+c] + sum_j k_j w1[j][c0+c])
    float a[12];
    #pragma unroll
    for (int c = 0; c < 12; ++c) a[c] = kj * w1r[c];
    wave_sum_batch<12>(a);
    #pragma unroll
    for (int c = 0; c < 12; ++c) a[c] = fmaxf(a[c] + rlane(b1o, c0 + c), 0.f);

    // partial layer2 output (half 0 carries the bias)
    float po = half ? 0.f : b2o;
    #pragma unroll
    for (int c = 0; c < 12; ++c) po = fmaf(a[c], w2c[c], po);

    // exchange partials (parity double-buffer -> one barrier per step)
    xbuf[sblk][step & 1][half][lane] = po;
    __syncthreads();
    float qo = xbuf[sblk][step & 1][half ^ 1][lane];
    float outv = po + qo;                 // commutative -> bitwise equal in both halves
    float dout = (outv - vj) * (2.f / 64.f);

    // dh[c] = sum_j w2[c0+c][j] dout_j
    float dh[12];
    #pragma unroll
    for (int c = 0; c < 12; ++c) dh[c] = w2c[c] * dout;
    wave_sum_batch<12>(dh);

    float dpre_own = 0.f;
    #pragma unroll
    for (int c = 0; c < 12; ++c) {
      float dp = (a[c] > 0.f) ? dh[c] : 0.f;
      dh[c] = dp;
      if (lane == c0 + c) dpre_own = dp;
    }

    #pragma unroll
    for (int c = 0; c < 12; ++c) {
      adam1(w1r[c], m1[c], v1[c], kj * dh[c], lrrc1, rc2);   // gw1[j][c0+c]
      adam1(w2c[c], m2[c], v2[c], a[c] * dout, lrrc1, rc2);  // gw2[c0+c][j]
    }
    adam1(b1o, mb1, vb1, dpre_own, lrrc1, rc2);  // zero-grad no-op outside own range
    adam1(b2o, mb2, vb2, dout, lrrc1, rc2);      // identical trajectory in both halves

    kj = kjn; vj = vjn;
  }

  // ---- query: enc[tok30] through finetuned MLP ----
  float qj = enc[q30 * 64 + lane];
  float a[12];
  #pragma unroll
  for (int c = 0; c < 12; ++c) a[c] = qj * w1r[c];
  wave_sum_batch<12>(a);
  #pragma unroll
  for (int c = 0; c < 12; ++c) a[c] = fmaxf(a[c] + rlane(b1o, c0 + c), 0.f);
  float po = half ? 0.f : b2o;
  #pragma unroll
  for (int c = 0; c < 12; ++c) po = fmaf(a[c], w2c[c], po);

  xbuf[sblk][0][half][lane] = po;
  __syncthreads();
  float y = po + xbuf[sblk][0][half ^ 1][lane];   // full MLP output, bitwise equal

  // ---- output head, split over l: this half sums 32 of the 64 terms ----
  float acc = 0.f;
  #pragma unroll
  for (int i = 0; i < 32; ++i) {
    int l = half * 32 + i;
    acc = fmaf(rlane(y, l), out_w[l * 64 + lane], acc);
  }
  xbuf[sblk][1][half][lane] = acc;
  __syncthreads();
  if (half == 0) {
    float tot = acc + xbuf[sblk][1][1][lane] + out_b[lane];
    out[(size_t)sample * 64 + lane] = tot;
  }
}

extern "C" void kernel_launch(void* const* d_in, const int* in_sizes, int n_in,
                              void* d_out, int out_size, void* d_ws, size_t ws_size,
                              hipStream_t stream) {
  const int*   seqs     = (const int*)d_in[0];
  const float* embed    = (const float*)d_in[1];
  const float* ff_w1    = (const float*)d_in[2];
  const float* ff_b1    = (const float*)d_in[3];
  const float* ff_w2    = (const float*)d_in[4];
  const float* ff_b2    = (const float*)d_in[5];
  const float* ln_g     = (const float*)d_in[6];
  const float* ln_b     = (const float*)d_in[7];
  const float* scorer_w = (const float*)d_in[8];
  const float* scorer_b = (const float*)d_in[9];
  const float* mlp_w1   = (const float*)d_in[10];
  const float* mlp_b1   = (const float*)d_in[11];
  const float* mlp_w2   = (const float*)d_in[12];
  const float* mlp_b2   = (const float*)d_in[13];
  const float* out_w    = (const float*)d_in[14];
  const float* out_b    = (const float*)d_in[15];

  const int B = in_sizes[0] / 32;        // 16384
  float* enc = (float*)d_ws;             // 64*64 floats = 16 KB
  float* sAt = enc + 64 * 64;            // 64 floats
  float* sBt = sAt + 64;                 // 64 floats

  enc_kernel<<<64, 64, 0, stream>>>(embed, ff_w1, ff_b1, ff_w2, ff_b2,
                                    ln_g, ln_b, scorer_w, enc, sAt, sBt);
  adam_kernel<<<B / 2, 256, 0, stream>>>(seqs, enc, sAt, sBt, scorer_b,
                                         mlp_w1, mlp_b1, mlp_w2, mlp_b2,
                                         out_w, out_b, (float*)d_out);
}

// Round 7
// 411.206 us; speedup vs baseline: 1.6072x; 1.6072x over previous
//
#include <hip/hip_runtime.h>

#define LRC   0.05f
#define B1C   0.9f
#define B2C   0.999f
#define C1C   0.1f      // float(1 - 0.9)
#define C2C   0.001f    // float(1 - 0.999)
#define EPSC  1e-8f

typedef float v2f __attribute__((ext_vector_type(2)));

__device__ __forceinline__ v2f splat(float s) { v2f r; r.x = s; r.y = s; return r; }

__device__ __forceinline__ float rlane(float v, int l) {
  return __int_as_float(__builtin_amdgcn_readlane(__float_as_int(v), l));
}

template <int CTRL, int RMASK, bool BC>
__device__ __forceinline__ float dpp_add(float x) {
  int y = __builtin_amdgcn_update_dpp(0, __float_as_int(x), CTRL, RMASK, 0xF, BC);
  return x + __int_as_float(y);
}

// canonical 6-stage wave64 sum: row_shr 1/2/4/8 + row_bcast15 + row_bcast31,
// total lands in lane 63, broadcast via one readlane. 7 VALU per value.
__device__ __forceinline__ float wave_sum_repl(float x) {
  x = dpp_add<0x111, 0xF, true>(x);   // row_shr:1
  x = dpp_add<0x112, 0xF, true>(x);   // row_shr:2
  x = dpp_add<0x114, 0xF, true>(x);   // row_shr:4
  x = dpp_add<0x118, 0xF, true>(x);   // row_shr:8  -> lane15 of each row = row sum
  x = dpp_add<0x142, 0xa, false>(x);  // row_bcast15: rows 1,3 += lane15/47
  x = dpp_add<0x143, 0xc, false>(x);  // row_bcast31: rows 2,3 += lane31
  return rlane(x, 63);
}

// batch of N replicated wave sums, stage-interleaved for ILP
template <int N>
__device__ __forceinline__ void wave_sum_batch(float* a) {
  #pragma unroll
  for (int c = 0; c < N; ++c) a[c] = dpp_add<0x111, 0xF, true>(a[c]);
  #pragma unroll
  for (int c = 0; c < N; ++c) a[c] = dpp_add<0x112, 0xF, true>(a[c]);
  #pragma unroll
  for (int c = 0; c < N; ++c) a[c] = dpp_add<0x114, 0xF, true>(a[c]);
  #pragma unroll
  for (int c = 0; c < N; ++c) a[c] = dpp_add<0x118, 0xF, true>(a[c]);
  #pragma unroll
  for (int c = 0; c < N; ++c) a[c] = dpp_add<0x142, 0xa, false>(a[c]);
  #pragma unroll
  for (int c = 0; c < N; ++c) a[c] = dpp_add<0x143, 0xc, false>(a[c]);
  #pragma unroll
  for (int c = 0; c < N; ++c) a[c] = rlane(a[c], 63);
}

// bias-correction constants: 1/(1-b^t), t=1..8
__constant__ float RC1T[8] = {10.0f, 5.2631578947f, 3.6900369004f, 2.9078220413f,
                              2.4419428585f, 2.1342007905f, 1.9167972515f, 1.7558143540f};
__constant__ float RC2T[8] = {1000.0f, 500.2501251f, 333.6669446f, 250.3753310f,
                              200.4003604f, 167.0837822f, 143.2862774f, 125.4381714f};

// ---------------- K1: encode table for the 64 distinct tokens ----------------
__global__ void enc_kernel(
    const float* __restrict__ embed,
    const float* __restrict__ ff_w1, const float* __restrict__ ff_b1,
    const float* __restrict__ ff_w2, const float* __restrict__ ff_b2,
    const float* __restrict__ ln_g, const float* __restrict__ ln_b,
    const float* __restrict__ scorer_w,
    float* __restrict__ enc, float* __restrict__ sAt, float* __restrict__ sBt)
{
  const int b = blockIdx.x;      // token id
  const int lane = threadIdx.x;  // feature

  float e = embed[b * 64 + lane];
  float acc0 = ff_b1[lane], acc1 = ff_b1[64 + lane];
  #pragma unroll
  for (int j = 0; j < 64; ++j) {
    float ej = rlane(e, j);
    acc0 = fmaf(ej, ff_w1[j * 128 + lane], acc0);
    acc1 = fmaf(ej, ff_w1[j * 128 + 64 + lane], acc1);
  }
  acc0 = fmaxf(acc0, 0.f);
  acc1 = fmaxf(acc1, 0.f);

  float f = ff_b2[lane];
  #pragma unroll
  for (int l = 0; l < 64; ++l) {
    f = fmaf(rlane(acc0, l), ff_w2[l * 64 + lane], f);
    f = fmaf(rlane(acc1, l), ff_w2[(l + 64) * 64 + lane], f);
  }

  float x = e + f;
  float mu = wave_sum_repl(x) * (1.f / 64.f);
  float d = x - mu;
  float var = wave_sum_repl(d * d) * (1.f / 64.f);
  float h = d * (1.f / sqrtf(var + 1e-5f)) * ln_g[lane] + ln_b[lane];
  enc[b * 64 + lane] = h;

  float sa = wave_sum_repl(h * scorer_w[lane]);
  float sb = wave_sum_repl(h * scorer_w[64 + lane]);
  if (lane == 0) { sAt[b] = sa; sBt[b] = sb; }
}

// ---------------- Adam updates: scalar and packed-pair ----------------
__device__ __forceinline__ void adam1(float& p, float& m, float& v, float g,
                                      float lrrc1, float rc2) {
  m = fmaf(B1C, m, C1C * g);
  v = fmaf(B2C, v, (C2C * g) * g);
  float den = __builtin_amdgcn_sqrtf(v * rc2) + EPSC;
  p = fmaf(-lrrc1, m * __builtin_amdgcn_rcpf(den), p);
}

__device__ __forceinline__ void adam2(v2f& p, v2f& m, v2f& v, v2f g,
                                      float lrrc1, float rc2) {
  m = __builtin_elementwise_fma(m, splat(B1C), g * splat(C1C));
  v = __builtin_elementwise_fma(v, splat(B2C), (g * splat(C2C)) * g);
  v2f x = v * splat(rc2);
  v2f den; den.x = __builtin_amdgcn_sqrtf(x.x) + EPSC;
           den.y = __builtin_amdgcn_sqrtf(x.y) + EPSC;
  v2f inv; inv.x = __builtin_amdgcn_rcpf(den.x);
           inv.y = __builtin_amdgcn_rcpf(den.y);
  p = __builtin_elementwise_fma(m * inv, splat(-lrrc1), p);
}

// ---------------- K2: two waves per sample, hidden units split 12/12 ----------------
// Per-lane param state as 6 float2 pairs per matrix -> v_pk_* packed FP32.
__global__ __launch_bounds__(256, 3) void adam_kernel(
    const int* __restrict__ seqs, const float* __restrict__ enc,
    const float* __restrict__ sAt, const float* __restrict__ sBt,
    const float* __restrict__ scorer_b,
    const float* __restrict__ mlp_w1, const float* __restrict__ mlp_b1,
    const float* __restrict__ mlp_w2, const float* __restrict__ mlp_b2,
    const float* __restrict__ out_w, const float* __restrict__ out_b,
    float* __restrict__ out)
{
  const int wid  = threadIdx.x >> 6;
  const int lane = threadIdx.x & 63;
  const int sblk = wid >> 1;           // sample within block
  const int half = wid & 1;            // which 12 hidden units we own
  const int c0   = half * 12;
  const int sample = blockIdx.x * 2 + sblk;

  __shared__ float xbuf[2][2][2][64];  // [sblk][parity][half][lane]

  int tv = seqs[sample * 32 + (lane & 31)];
  float sbv = scorer_b[0];

  // scores from factored tables (wave-uniform)
  float sc[15]; int ta[15], tb[15];
  #pragma unroll
  for (int p = 0; p < 15; ++p) {
    ta[p] = __builtin_amdgcn_readlane(tv, 2 * p);
    tb[p] = __builtin_amdgcn_readlane(tv, 2 * p + 1);
    sc[p] = sAt[ta[p]] + sBt[tb[p]] + sbv;
  }
  int q30 = __builtin_amdgcn_readlane(tv, 30);

  // evict-min on (score, token-id); strict < keeps FIRST min
  float bs[8]; int bka[8], bva[8];
  #pragma unroll
  for (int i = 0; i < 8; ++i) { bs[i] = sc[i]; bka[i] = ta[i]; bva[i] = tb[i]; }
  #pragma unroll
  for (int n = 0; n < 7; ++n) {
    int mi = 0; float ms = bs[0];
    #pragma unroll
    for (int i = 1; i < 8; ++i) {
      if (bs[i] < ms) { mi = i; ms = bs[i]; }
    }
    #pragma unroll
    for (int i = 0; i < 7; ++i) {
      bool sh = i >= mi;
      bs[i]  = sh ? bs[i + 1]  : bs[i];
      bka[i] = sh ? bka[i + 1] : bka[i];
      bva[i] = sh ? bva[i + 1] : bva[i];
    }
    bs[7] = sc[8 + n]; bka[7] = ta[8 + n]; bva[7] = tb[8 + n];
  }

  // own params as packed pairs: w1r2[i] = w1[lane][c0+2i .. c0+2i+1],
  // w2c2[i] = w2[c0+2i][lane], w2[c0+2i+1][lane]
  v2f w1r2[6], w2c2[6], m1[6], v1[6], m2[6], v2[6];
  #pragma unroll
  for (int i = 0; i < 6; ++i) {
    v2f t;
    t.x = mlp_w1[lane * 24 + c0 + 2 * i];
    t.y = mlp_w1[lane * 24 + c0 + 2 * i + 1];
    w1r2[i] = t;
    t.x = mlp_w2[(c0 + 2 * i) * 64 + lane];
    t.y = mlp_w2[(c0 + 2 * i + 1) * 64 + lane];
    w2c2[i] = t;
    m1[i] = splat(0.f); v1[i] = splat(0.f); m2[i] = splat(0.f); v2[i] = splat(0.f);
  }
  float b1o = (lane >= c0 && lane < c0 + 12) ? mlp_b1[lane] : 0.f;
  float b2o = mlp_b2[lane];
  float mb1 = 0.f, vb1 = 0.f, mb2 = 0.f, vb2 = 0.f;

  float kj = enc[bka[0] * 64 + lane];
  float vj = enc[bva[0] * 64 + lane];

  #pragma unroll 1
  for (int step = 0; step < 8; ++step) {
    // prefetch next step's (k,v) pair
    int nidx = (step < 7) ? step + 1 : 7;
    int kan = bka[0], van = bva[0];
    #pragma unroll
    for (int i = 1; i < 8; ++i)
      if (nidx == i) { kan = bka[i]; van = bva[i]; }
    float kjn = enc[kan * 64 + lane];
    float vjn = enc[van * 64 + lane];

    float lrrc1 = LRC * RC1T[step];
    float rc2 = RC2T[step];

    // layer1 products (packed), then 12-value DPP reduction
    v2f kj2 = splat(kj);
    float a[12];
    #pragma unroll
    for (int i = 0; i < 6; ++i) {
      v2f p2 = kj2 * w1r2[i];
      a[2 * i] = p2.x; a[2 * i + 1] = p2.y;
    }
    wave_sum_batch<12>(a);

    // bias + relu (packed)
    v2f a2[6];
    #pragma unroll
    for (int i = 0; i < 6; ++i) {
      v2f t; t.x = a[2 * i] + rlane(b1o, c0 + 2 * i);
             t.y = a[2 * i + 1] + rlane(b1o, c0 + 2 * i + 1);
      a2[i] = __builtin_elementwise_max(t, splat(0.f));
    }

    // partial layer2 output (half 0 carries the bias)
    v2f po2 = splat(0.f);
    #pragma unroll
    for (int i = 0; i < 6; ++i) po2 = __builtin_elementwise_fma(a2[i], w2c2[i], po2);
    float po = po2.x + po2.y + (half ? 0.f : b2o);

    // exchange partials (parity double-buffer -> one barrier per step)
    xbuf[sblk][step & 1][half][lane] = po;
    __syncthreads();
    float qo = xbuf[sblk][step & 1][half ^ 1][lane];
    float outv = po + qo;                 // commutative -> bitwise equal in both halves
    float dout = (outv - vj) * (2.f / 64.f);
    v2f dout2 = splat(dout);

    // dh[c] = sum_j w2[c0+c][j] dout_j (packed products, DPP reduce)
    float dh[12];
    #pragma unroll
    for (int i = 0; i < 6; ++i) {
      v2f d2 = w2c2[i] * dout2;
      dh[2 * i] = d2.x; dh[2 * i + 1] = d2.y;
    }
    wave_sum_batch<12>(dh);

    // dpre = dh * relu'(pre); own-lane pick for b1 grad
    float dpre_own = 0.f;
    v2f dp2[6];
    #pragma unroll
    for (int i = 0; i < 6; ++i) {
      float d0 = (a2[i].x > 0.f) ? dh[2 * i] : 0.f;
      float d1 = (a2[i].y > 0.f) ? dh[2 * i + 1] : 0.f;
      v2f t; t.x = d0; t.y = d1; dp2[i] = t;
      if (lane == c0 + 2 * i)     dpre_own = d0;
      if (lane == c0 + 2 * i + 1) dpre_own = d1;
    }

    // packed Adam updates
    #pragma unroll
    for (int i = 0; i < 6; ++i) {
      adam2(w1r2[i], m1[i], v1[i], kj2 * dp2[i], lrrc1, rc2);     // gw1[j][c]
      adam2(w2c2[i], m2[i], v2[i], a2[i] * dout2, lrrc1, rc2);    // gw2[c][j]
    }
    adam1(b1o, mb1, vb1, dpre_own, lrrc1, rc2);
    adam1(b2o, mb2, vb2, dout, lrrc1, rc2);

    kj = kjn; vj = vjn;
  }

  // ---- query: enc[tok30] through finetuned MLP ----
  float qj = enc[q30 * 64 + lane];
  v2f qj2 = splat(qj);
  float a[12];
  #pragma unroll
  for (int i = 0; i < 6; ++i) {
    v2f p2 = qj2 * w1r2[i];
    a[2 * i] = p2.x; a[2 * i + 1] = p2.y;
  }
  wave_sum_batch<12>(a);
  v2f a2[6];
  #pragma unroll
  for (int i = 0; i < 6; ++i) {
    v2f t; t.x = a[2 * i] + rlane(b1o, c0 + 2 * i);
           t.y = a[2 * i + 1] + rlane(b1o, c0 + 2 * i + 1);
    a2[i] = __builtin_elementwise_max(t, splat(0.f));
  }
  v2f po2 = splat(0.f);
  #pragma unroll
  for (int i = 0; i < 6; ++i) po2 = __builtin_elementwise_fma(a2[i], w2c2[i], po2);
  float po = po2.x + po2.y + (half ? 0.f : b2o);

  xbuf[sblk][0][half][lane] = po;
  __syncthreads();
  float y = po + xbuf[sblk][0][half ^ 1][lane];   // full MLP output, bitwise equal

  // ---- output head, split over l: this half sums 32 of the 64 terms ----
  v2f acc2 = splat(0.f);
  #pragma unroll
  for (int i = 0; i < 16; ++i) {
    int l = half * 32 + 2 * i;
    v2f yw; yw.x = rlane(y, l); yw.y = rlane(y, l + 1);
    v2f ww; ww.x = out_w[l * 64 + lane]; ww.y = out_w[(l + 1) * 64 + lane];
    acc2 = __builtin_elementwise_fma(yw, ww, acc2);
  }
  float acc = acc2.x + acc2.y;
  xbuf[sblk][1][half][lane] = acc;
  __syncthreads();
  if (half == 0) {
    float tot = acc + xbuf[sblk][1][1][lane] + out_b[lane];
    out[(size_t)sample * 64 + lane] = tot;
  }
}

extern "C" void kernel_launch(void* const* d_in, const int* in_sizes, int n_in,
                              void* d_out, int out_size, void* d_ws, size_t ws_size,
                              hipStream_t stream) {
  const int*   seqs     = (const int*)d_in[0];
  const float* embed    = (const float*)d_in[1];
  const float* ff_w1    = (const float*)d_in[2];
  const float* ff_b1    = (const float*)d_in[3];
  const float* ff_w2    = (const float*)d_in[4];
  const float* ff_b2    = (const float*)d_in[5];
  const float* ln_g     = (const float*)d_in[6];
  const float* ln_b     = (const float*)d_in[7];
  const float* scorer_w = (const float*)d_in[8];
  const float* scorer_b = (const float*)d_in[9];
  const float* mlp_w1   = (const float*)d_in[10];
  const float* mlp_b1   = (const float*)d_in[11];
  const float* mlp_w2   = (const float*)d_in[12];
  const float* mlp_b2   = (const float*)d_in[13];
  const float* out_w    = (const float*)d_in[14];
  const float* out_b    = (const float*)d_in[15];

  const int B = in_sizes[0] / 32;        // 16384
  float* enc = (float*)d_ws;             // 64*64 floats = 16 KB
  float* sAt = enc + 64 * 64;            // 64 floats
  float* sBt = sAt + 64;                 // 64 floats

  enc_kernel<<<64, 64, 0, stream>>>(embed, ff_w1, ff_b1, ff_w2, ff_b2,
                                    ln_g, ln_b, scorer_w, enc, sAt, sBt);
  adam_kernel<<<B / 2, 256, 0, stream>>>(seqs, enc, sAt, sBt, scorer_b,
                                         mlp_w1, mlp_b1, mlp_w2, mlp_b2,
                                         out_w, out_b, (float*)d_out);
}

// Round 8
// 358.379 us; speedup vs baseline: 1.8441x; 1.1474x over previous
//
#include <hip/hip_runtime.h>

#define LRC   0.05f
#define B1C   0.9f
#define B2C   0.999f
#define C1C   0.1f      // float(1 - 0.9)
#define C2C   0.001f    // float(1 - 0.999)
#define EPSC  1e-8f

typedef float v2f __attribute__((ext_vector_type(2)));

__device__ __forceinline__ v2f splat(float s) { v2f r; r.x = s; r.y = s; return r; }

__device__ __forceinline__ float rlane(float v, int l) {
  return __int_as_float(__builtin_amdgcn_readlane(__float_as_int(v), l));
}

template <int CTRL, int RMASK, bool BC>
__device__ __forceinline__ float dpp_add(float x) {
  int y = __builtin_amdgcn_update_dpp(0, __float_as_int(x), CTRL, RMASK, 0xF, BC);
  return x + __int_as_float(y);
}

// canonical 6-stage wave64 sum -> lane63, then readlane broadcast (7 VALU/value)
__device__ __forceinline__ float wave_sum_repl(float x) {
  x = dpp_add<0x111, 0xF, true>(x);   // row_shr:1
  x = dpp_add<0x112, 0xF, true>(x);   // row_shr:2
  x = dpp_add<0x114, 0xF, true>(x);   // row_shr:4
  x = dpp_add<0x118, 0xF, true>(x);   // row_shr:8
  x = dpp_add<0x142, 0xa, false>(x);  // row_bcast15
  x = dpp_add<0x143, 0xc, false>(x);  // row_bcast31
  return rlane(x, 63);
}

template <int N>
__device__ __forceinline__ void wave_sum_batch(float* a) {
  #pragma unroll
  for (int c = 0; c < N; ++c) a[c] = dpp_add<0x111, 0xF, true>(a[c]);
  #pragma unroll
  for (int c = 0; c < N; ++c) a[c] = dpp_add<0x112, 0xF, true>(a[c]);
  #pragma unroll
  for (int c = 0; c < N; ++c) a[c] = dpp_add<0x114, 0xF, true>(a[c]);
  #pragma unroll
  for (int c = 0; c < N; ++c) a[c] = dpp_add<0x118, 0xF, true>(a[c]);
  #pragma unroll
  for (int c = 0; c < N; ++c) a[c] = dpp_add<0x142, 0xa, false>(a[c]);
  #pragma unroll
  for (int c = 0; c < N; ++c) a[c] = dpp_add<0x143, 0xc, false>(a[c]);
  #pragma unroll
  for (int c = 0; c < N; ++c) a[c] = rlane(a[c], 63);
}

// ---------------- K1: encode table for the 64 distinct tokens ----------------
__global__ void enc_kernel(
    const float* __restrict__ embed,
    const float* __restrict__ ff_w1, const float* __restrict__ ff_b1,
    const float* __restrict__ ff_w2, const float* __restrict__ ff_b2,
    const float* __restrict__ ln_g, const float* __restrict__ ln_b,
    const float* __restrict__ scorer_w,
    float* __restrict__ enc, float* __restrict__ sAt, float* __restrict__ sBt)
{
  const int b = blockIdx.x;      // token id
  const int lane = threadIdx.x;  // feature

  float e = embed[b * 64 + lane];
  float acc0 = ff_b1[lane], acc1 = ff_b1[64 + lane];
  #pragma unroll
  for (int j = 0; j < 64; ++j) {
    float ej = rlane(e, j);
    acc0 = fmaf(ej, ff_w1[j * 128 + lane], acc0);
    acc1 = fmaf(ej, ff_w1[j * 128 + 64 + lane], acc1);
  }
  acc0 = fmaxf(acc0, 0.f);
  acc1 = fmaxf(acc1, 0.f);

  float f = ff_b2[lane];
  #pragma unroll
  for (int l = 0; l < 64; ++l) {
    f = fmaf(rlane(acc0, l), ff_w2[l * 64 + lane], f);
    f = fmaf(rlane(acc1, l), ff_w2[(l + 64) * 64 + lane], f);
  }

  float x = e + f;
  float mu = wave_sum_repl(x) * (1.f / 64.f);
  float d = x - mu;
  float var = wave_sum_repl(d * d) * (1.f / 64.f);
  float h = d * (1.f / sqrtf(var + 1e-5f)) * ln_g[lane] + ln_b[lane];
  enc[b * 64 + lane] = h;

  float sa = wave_sum_repl(h * scorer_w[lane]);
  float sb = wave_sum_repl(h * scorer_w[64 + lane]);
  if (lane == 0) { sAt[b] = sa; sBt[b] = sb; }
}

// ---------------- Adam updates ----------------
// scalar: exact sqrt+eps form (used for the 2 bias params only)
__device__ __forceinline__ void adam1(float& p, float& m, float& v, float g,
                                      float lrrc1, float rc2) {
  m = fmaf(B1C, m, C1C * g);
  v = fmaf(B2C, v, (C2C * g) * g);
  float den = __builtin_amdgcn_sqrtf(v * rc2) + EPSC;
  p = fmaf(-lrrc1, m * __builtin_amdgcn_rcpf(den), p);
}

// packed: rsqrt form (eps dropped; guarded against v==0 -> exact 0 update since m==0)
__device__ __forceinline__ void adam2(v2f& p, v2f& m, v2f& v, v2f g,
                                      float lrrc1, float rc2) {
  m = __builtin_elementwise_fma(m, splat(B1C), g * splat(C1C));
  v = __builtin_elementwise_fma(v, splat(B2C), (g * splat(C2C)) * g);
  v2f x = __builtin_elementwise_max(v * splat(rc2), splat(1e-30f));
  v2f r; r.x = __builtin_amdgcn_rsqf(x.x);
         r.y = __builtin_amdgcn_rsqf(x.y);
  p = __builtin_elementwise_fma(m * r, splat(-lrrc1), p);
}

// ---------------- K2: two waves per sample, hidden units split 12/12 ----------------
// Control path (scores/evict/pair-select) on SALU via sortable uint keys;
// 8 Adam steps fully unrolled; b1-bias and dpre-extraction via one-hot masks.
__global__ __launch_bounds__(256, 3) void adam_kernel(
    const int* __restrict__ seqs, const float* __restrict__ enc,
    const float* __restrict__ sAt, const float* __restrict__ sBt,
    const float* __restrict__ scorer_b,
    const float* __restrict__ mlp_w1, const float* __restrict__ mlp_b1,
    const float* __restrict__ mlp_w2, const float* __restrict__ mlp_b2,
    const float* __restrict__ out_w, const float* __restrict__ out_b,
    float* __restrict__ out)
{
  const int wid  = threadIdx.x >> 6;
  const int lane = threadIdx.x & 63;
  const int sblk = wid >> 1;           // sample within block
  const int half = wid & 1;            // which 12 hidden units we own
  const int c0   = half * 12;
  const int sample = blockIdx.x * 2 + sblk;

  __shared__ float xbuf[2][2][2][64];  // [sblk][parity][half][lane]

  constexpr float RC1T[8] = {10.0f, 5.2631578947f, 3.6900369004f, 2.9078220413f,
                             2.4419428585f, 2.1342007905f, 1.9167972515f, 1.7558143540f};
  constexpr float RC2T[8] = {1000.0f, 500.2501251f, 333.6669446f, 250.3753310f,
                             200.4003604f, 167.0837822f, 143.2862774f, 125.4381714f};

  int tv = seqs[sample * 32 + (lane & 31)];
  float sbv = scorer_b[0];

  // scores -> sortable uint keys, pinned to SGPRs (evict-min runs on SALU)
  unsigned skey[15]; int ta[15], tb[15];
  #pragma unroll
  for (int p = 0; p < 15; ++p) {
    ta[p] = __builtin_amdgcn_readfirstlane(__builtin_amdgcn_readlane(tv, 2 * p));
    tb[p] = __builtin_amdgcn_readfirstlane(__builtin_amdgcn_readlane(tv, 2 * p + 1));
    float s = sAt[ta[p]] + sBt[tb[p]] + sbv;
    unsigned u = __float_as_uint(s);
    unsigned k = u ^ (((unsigned)((int)u >> 31)) | 0x80000000u);
    skey[p] = __builtin_amdgcn_readfirstlane((int)k);
  }
  int q30 = __builtin_amdgcn_readfirstlane(__builtin_amdgcn_readlane(tv, 30));

  // evict-min on uniform (key, tok, tok); strict < keeps FIRST min
  unsigned bs[8]; int bka[8], bva[8];
  #pragma unroll
  for (int i = 0; i < 8; ++i) { bs[i] = skey[i]; bka[i] = ta[i]; bva[i] = tb[i]; }
  #pragma unroll
  for (int n = 0; n < 7; ++n) {
    int mi = 0; unsigned ms = bs[0];
    #pragma unroll
    for (int i = 1; i < 8; ++i) {
      if (bs[i] < ms) { mi = i; ms = bs[i]; }
    }
    #pragma unroll
    for (int i = 0; i < 7; ++i) {
      bool sh = i >= mi;
      bs[i]  = sh ? bs[i + 1]  : bs[i];
      bka[i] = sh ? bka[i + 1] : bka[i];
      bva[i] = sh ? bva[i + 1] : bva[i];
    }
    bs[7] = skey[8 + n]; bka[7] = ta[8 + n]; bva[7] = tb[8 + n];
  }

  // preload all 8 (k,v) rows (SGPR base + lane offset, L1-resident table)
  float kjv[8], vjv[8];
  #pragma unroll
  for (int i = 0; i < 8; ++i) {
    kjv[i] = enc[bka[i] * 64 + lane];
    vjv[i] = enc[bva[i] * 64 + lane];
  }

  // params as packed pairs
  v2f w1r2[6], w2c2[6], m1[6], v1[6], m2[6], v2[6];
  #pragma unroll
  for (int i = 0; i < 6; ++i) {
    v2f t;
    t.x = mlp_w1[lane * 24 + c0 + 2 * i];
    t.y = mlp_w1[lane * 24 + c0 + 2 * i + 1];
    w1r2[i] = t;
    t.x = mlp_w2[(c0 + 2 * i) * 64 + lane];
    t.y = mlp_w2[(c0 + 2 * i + 1) * 64 + lane];
    w2c2[i] = t;
    m1[i] = splat(0.f); v1[i] = splat(0.f); m2[i] = splat(0.f); v2[i] = splat(0.f);
  }
  // one-hot lane masks: bm2[i] = ((lane==c0+2i)?1:0, (lane==c0+2i+1)?1:0)
  v2f bm2[6];
  #pragma unroll
  for (int i = 0; i < 6; ++i) {
    v2f t; t.x = (lane == c0 + 2 * i) ? 1.f : 0.f;
           t.y = (lane == c0 + 2 * i + 1) ? 1.f : 0.f;
    bm2[i] = t;
  }
  float b1o = (lane >= c0 && lane < c0 + 12) ? mlp_b1[lane] : 0.f;
  float b2o = mlp_b2[lane];
  float mb1 = 0.f, vb1 = 0.f, mb2 = 0.f, vb2 = 0.f;

  #pragma unroll
  for (int step = 0; step < 8; ++step) {
    const float lrrc1 = LRC * RC1T[step];
    const float rc2 = RC2T[step];
    const float kj = kjv[step], vj = vjv[step];
    v2f kj2 = splat(kj);
    v2f b1o2 = splat(b1o);

    // layer1 products with bias folded in via one-hot masks
    float a[12];
    #pragma unroll
    for (int i = 0; i < 6; ++i) {
      v2f p2 = __builtin_elementwise_fma(kj2, w1r2[i], bm2[i] * b1o2);
      a[2 * i] = p2.x; a[2 * i + 1] = p2.y;
    }
    wave_sum_batch<12>(a);

    // relu (scalar max off the broadcast value)
    v2f a2[6];
    #pragma unroll
    for (int i = 0; i < 6; ++i) {
      v2f t; t.x = fmaxf(a[2 * i], 0.f); t.y = fmaxf(a[2 * i + 1], 0.f);
      a2[i] = t;
    }

    // partial layer2 output (half 0 carries the bias)
    v2f po2 = splat(0.f);
    #pragma unroll
    for (int i = 0; i < 6; ++i) po2 = __builtin_elementwise_fma(a2[i], w2c2[i], po2);
    float po = po2.x + po2.y + (half ? 0.f : b2o);

    // exchange partials (parity double-buffer -> one barrier per step)
    xbuf[sblk][step & 1][half][lane] = po;
    __syncthreads();
    float qo = xbuf[sblk][step & 1][half ^ 1][lane];
    float outv = po + qo;                 // commutative -> bitwise equal in both halves
    float dout = (outv - vj) * (2.f / 64.f);
    v2f dout2 = splat(dout);

    // dh[c] = sum_j w2[c][j] dout_j
    float dh[12];
    #pragma unroll
    for (int i = 0; i < 6; ++i) {
      v2f d2 = w2c2[i] * dout2;
      dh[2 * i] = d2.x; dh[2 * i + 1] = d2.y;
    }
    wave_sum_batch<12>(dh);

    // relu gate arithmetically: gate = min(a2*1e30, 1) in {0,1}
    v2f dp2[6];
    #pragma unroll
    for (int i = 0; i < 6; ++i) {
      v2f gate = __builtin_elementwise_min(a2[i] * splat(1e30f), splat(1.f));
      v2f t; t.x = dh[2 * i]; t.y = dh[2 * i + 1];
      dp2[i] = gate * t;
    }
    // dpre_own = sum_c onehot[c]*dp[c]
    v2f ow2 = splat(0.f);
    #pragma unroll
    for (int i = 0; i < 6; ++i) ow2 = __builtin_elementwise_fma(bm2[i], dp2[i], ow2);
    float dpre_own = ow2.x + ow2.y;

    // packed Adam updates
    #pragma unroll
    for (int i = 0; i < 6; ++i) {
      adam2(w1r2[i], m1[i], v1[i], kj2 * dp2[i], lrrc1, rc2);     // gw1[j][c]
      adam2(w2c2[i], m2[i], v2[i], a2[i] * dout2, lrrc1, rc2);    // gw2[c][j]
    }
    adam1(b1o, mb1, vb1, dpre_own, lrrc1, rc2);
    adam1(b2o, mb2, vb2, dout, lrrc1, rc2);
  }

  // ---- query: enc[tok30] through finetuned MLP ----
  float qj = enc[q30 * 64 + lane];
  v2f qj2 = splat(qj);
  v2f b1o2 = splat(b1o);
  float a[12];
  #pragma unroll
  for (int i = 0; i < 6; ++i) {
    v2f p2 = __builtin_elementwise_fma(qj2, w1r2[i], bm2[i] * b1o2);
    a[2 * i] = p2.x; a[2 * i + 1] = p2.y;
  }
  wave_sum_batch<12>(a);
  v2f po2 = splat(0.f);
  #pragma unroll
  for (int i = 0; i < 6; ++i) {
    v2f t; t.x = fmaxf(a[2 * i], 0.f); t.y = fmaxf(a[2 * i + 1], 0.f);
    po2 = __builtin_elementwise_fma(t, w2c2[i], po2);
  }
  float po = po2.x + po2.y + (half ? 0.f : b2o);

  xbuf[sblk][0][half][lane] = po;
  __syncthreads();
  float y = po + xbuf[sblk][0][half ^ 1][lane];   // full MLP output, bitwise equal

  // ---- output head, split over l: this half sums 32 of the 64 terms ----
  float acc = 0.f;
  #pragma unroll
  for (int i = 0; i < 32; ++i) {
    int l = half * 32 + i;
    acc = fmaf(rlane(y, l), out_w[l * 64 + lane], acc);
  }
  xbuf[sblk][1][half][lane] = acc;
  __syncthreads();
  if (half == 0) {
    float tot = acc + xbuf[sblk][1][1][lane] + out_b[lane];
    out[(size_t)sample * 64 + lane] = tot;
  }
}

extern "C" void kernel_launch(void* const* d_in, const int* in_sizes, int n_in,
                              void* d_out, int out_size, void* d_ws, size_t ws_size,
                              hipStream_t stream) {
  const int*   seqs     = (const int*)d_in[0];
  const float* embed    = (const float*)d_in[1];
  const float* ff_w1    = (const float*)d_in[2];
  const float* ff_b1    = (const float*)d_in[3];
  const float* ff_w2    = (const float*)d_in[4];
  const float* ff_b2    = (const float*)d_in[5];
  const float* ln_g     = (const float*)d_in[6];
  const float* ln_b     = (const float*)d_in[7];
  const float* scorer_w = (const float*)d_in[8];
  const float* scorer_b = (const float*)d_in[9];
  const float* mlp_w1   = (const float*)d_in[10];
  const float* mlp_b1   = (const float*)d_in[11];
  const float* mlp_w2   = (const float*)d_in[12];
  const float* mlp_b2   = (const float*)d_in[13];
  const float* out_w    = (const float*)d_in[14];
  const float* out_b    = (const float*)d_in[15];

  const int B = in_sizes[0] / 32;        // 16384
  float* enc = (float*)d_ws;             // 64*64 floats = 16 KB
  float* sAt = enc + 64 * 64;            // 64 floats
  float* sBt = sAt + 64;                 // 64 floats

  enc_kernel<<<64, 64, 0, stream>>>(embed, ff_w1, ff_b1, ff_w2, ff_b2,
                                    ln_g, ln_b, scorer_w, enc, sAt, sBt);
  adam_kernel<<<B / 2, 256, 0, stream>>>(seqs, enc, sAt, sBt, scorer_b,
                                         mlp_w1, mlp_b1, mlp_w2, mlp_b2,
                                         out_w, out_b, (float*)d_out);
}

// Round 9
// 242.636 us; speedup vs baseline: 2.7238x; 1.4770x over previous
//
#include <hip/hip_runtime.h>

#define LRC   0.05f
#define B1C   0.9f
#define B2C   0.999f
#define C1C   0.1f      // float(1 - 0.9)
#define C2C   0.001f    // float(1 - 0.999)
#define EPSC  1e-8f

typedef float v2f __attribute__((ext_vector_type(2)));

__device__ __forceinline__ v2f splat(float s) { v2f r; r.x = s; r.y = s; return r; }

__device__ __forceinline__ float rlane(float v, int l) {
  return __int_as_float(__builtin_amdgcn_readlane(__float_as_int(v), l));
}

template <int CTRL, int RMASK, bool BC>
__device__ __forceinline__ float dpp_add(float x) {
  int y = __builtin_amdgcn_update_dpp(0, __float_as_int(x), CTRL, RMASK, 0xF, BC);
  return x + __int_as_float(y);
}

template <int OFF>
__device__ __forceinline__ float dswz(float x) {
  return __int_as_float(__builtin_amdgcn_ds_swizzle(__float_as_int(x), OFF));
}
__device__ __forceinline__ float bperm(int addr, float x) {
  return __int_as_float(__builtin_amdgcn_ds_bpermute(addr, __float_as_int(x)));
}

// 4-stage 16-lane row prefix sum; row total lands in lanes 15/31/47/63
template <int N>
__device__ __forceinline__ void row_sum_batch(float* a) {
  #pragma unroll
  for (int c = 0; c < N; ++c) a[c] = dpp_add<0x111, 0xF, true>(a[c]);
  #pragma unroll
  for (int c = 0; c < N; ++c) a[c] = dpp_add<0x112, 0xF, true>(a[c]);
  #pragma unroll
  for (int c = 0; c < N; ++c) a[c] = dpp_add<0x114, 0xF, true>(a[c]);
  #pragma unroll
  for (int c = 0; c < N; ++c) a[c] = dpp_add<0x118, 0xF, true>(a[c]);
}

// full-wave sum replicated (enc_kernel only)
__device__ __forceinline__ float wave_sum_repl(float x) {
  x = dpp_add<0x111, 0xF, true>(x);
  x = dpp_add<0x112, 0xF, true>(x);
  x = dpp_add<0x114, 0xF, true>(x);
  x = dpp_add<0x118, 0xF, true>(x);
  x = dpp_add<0x142, 0xa, false>(x);
  x = dpp_add<0x143, 0xc, false>(x);
  return rlane(x, 63);
}

// ---------------- K1: encode table for the 64 distinct tokens ----------------
__global__ void enc_kernel(
    const float* __restrict__ embed,
    const float* __restrict__ ff_w1, const float* __restrict__ ff_b1,
    const float* __restrict__ ff_w2, const float* __restrict__ ff_b2,
    const float* __restrict__ ln_g, const float* __restrict__ ln_b,
    const float* __restrict__ scorer_w,
    float* __restrict__ enc, float* __restrict__ sAt, float* __restrict__ sBt)
{
  const int b = blockIdx.x;      // token id
  const int lane = threadIdx.x;  // feature

  float e = embed[b * 64 + lane];
  float acc0 = ff_b1[lane], acc1 = ff_b1[64 + lane];
  #pragma unroll
  for (int j = 0; j < 64; ++j) {
    float ej = rlane(e, j);
    acc0 = fmaf(ej, ff_w1[j * 128 + lane], acc0);
    acc1 = fmaf(ej, ff_w1[j * 128 + 64 + lane], acc1);
  }
  acc0 = fmaxf(acc0, 0.f);
  acc1 = fmaxf(acc1, 0.f);

  float f = ff_b2[lane];
  #pragma unroll
  for (int l = 0; l < 64; ++l) {
    f = fmaf(rlane(acc0, l), ff_w2[l * 64 + lane], f);
    f = fmaf(rlane(acc1, l), ff_w2[(l + 64) * 64 + lane], f);
  }

  float x = e + f;
  float mu = wave_sum_repl(x) * (1.f / 64.f);
  float d = x - mu;
  float var = wave_sum_repl(d * d) * (1.f / 64.f);
  float h = d * (1.f / sqrtf(var + 1e-5f)) * ln_g[lane] + ln_b[lane];
  enc[b * 64 + lane] = h;

  float sa = wave_sum_repl(h * scorer_w[lane]);
  float sb = wave_sum_repl(h * scorer_w[64 + lane]);
  if (lane == 0) { sAt[b] = sa; sBt[b] = sb; }
}

// ---------------- Adam update (packed pair, rsqrt form) ----------------
__device__ __forceinline__ void adam2(v2f& p, v2f& m, v2f& v, v2f g,
                                      float lrrc1, float rc2) {
  m = __builtin_elementwise_fma(m, splat(B1C), g * splat(C1C));
  v = __builtin_elementwise_fma(v, splat(B2C), (g * splat(C2C)) * g);
  v2f x = __builtin_elementwise_max(v * splat(rc2), splat(1e-30f));
  v2f r; r.x = __builtin_amdgcn_rsqf(x.x);
         r.y = __builtin_amdgcn_rsqf(x.y);
  p = __builtin_elementwise_fma(m * r, splat(-lrrc1), p);
}

// ---------------- K2: ONE wave per sample, 16 feat-lanes x 4 unit-rows ------
// lane = 16*ug + fl. Lane owns features j in {4fl..4fl+3} and units
// c in {6ug..6ug+5}. Contractions over j become 4-stage row reductions;
// cross-lane traffic is ds_swizzle/bpermute on the DS pipe. No barriers,
// no shared memory.
__global__ __launch_bounds__(256, 2) void adam_kernel(
    const int* __restrict__ seqs, const float* __restrict__ enc,
    const float* __restrict__ sAt, const float* __restrict__ sBt,
    const float* __restrict__ scorer_b,
    const float* __restrict__ mlp_w1, const float* __restrict__ mlp_b1,
    const float* __restrict__ mlp_w2, const float* __restrict__ mlp_b2,
    const float* __restrict__ out_w, const float* __restrict__ out_b,
    float* __restrict__ out)
{
  const int wid  = threadIdx.x >> 6;
  const int lane = threadIdx.x & 63;
  const int fl = lane & 15, ug = lane >> 4;
  const int c0 = 6 * ug, jb = 4 * fl;
  const int sample = blockIdx.x * 4 + wid;

  constexpr float RC1T[8] = {10.0f, 5.2631578947f, 3.6900369004f, 2.9078220413f,
                             2.4419428585f, 2.1342007905f, 1.9167972515f, 1.7558143540f};
  constexpr float RC2T[8] = {1000.0f, 500.2501251f, 333.6669446f, 250.3753310f,
                             200.4003604f, 167.0837822f, 143.2862774f, 125.4381714f};

  int tv = seqs[sample * 32 + (lane & 31)];
  float sbv = scorer_b[0];

  // scores -> sortable uint keys (uniform; evict-min on SALU)
  unsigned skey[15]; int ta[15], tb[15];
  #pragma unroll
  for (int p = 0; p < 15; ++p) {
    ta[p] = __builtin_amdgcn_readfirstlane(__builtin_amdgcn_readlane(tv, 2 * p));
    tb[p] = __builtin_amdgcn_readfirstlane(__builtin_amdgcn_readlane(tv, 2 * p + 1));
    float s = sAt[ta[p]] + sBt[tb[p]] + sbv;
    unsigned u = __float_as_uint(s);
    unsigned k = u ^ (((unsigned)((int)u >> 31)) | 0x80000000u);
    skey[p] = __builtin_amdgcn_readfirstlane((int)k);
  }
  int q30 = __builtin_amdgcn_readfirstlane(__builtin_amdgcn_readlane(tv, 30));

  // evict-min; strict < keeps FIRST min
  unsigned bs[8]; int bka[8], bva[8];
  #pragma unroll
  for (int i = 0; i < 8; ++i) { bs[i] = skey[i]; bka[i] = ta[i]; bva[i] = tb[i]; }
  #pragma unroll
  for (int n = 0; n < 7; ++n) {
    int mi = 0; unsigned ms = bs[0];
    #pragma unroll
    for (int i = 1; i < 8; ++i) {
      if (bs[i] < ms) { mi = i; ms = bs[i]; }
    }
    #pragma unroll
    for (int i = 0; i < 7; ++i) {
      bool sh = i >= mi;
      bs[i]  = sh ? bs[i + 1]  : bs[i];
      bka[i] = sh ? bka[i + 1] : bka[i];
      bva[i] = sh ? bva[i + 1] : bva[i];
    }
    bs[7] = skey[8 + n]; bka[7] = ta[8 + n]; bva[7] = tb[8 + n];
  }

  const float flm = (fl == 0) ? 1.f : 0.f;   // bias-owner masks (exact 1/0)
  const float ugm = (ug == 0) ? 1.f : 0.f;
  const int xaddr32 = (lane ^ 32) << 2;      // bpermute byte addr for xor-32
  const float S = 2.f / 64.f;

  // ---- params ----
  // w1p[m][p] = (w1[(jb+m)*24 + c0+2p], ..+1)   : cc-pairs
  // w2p[cc][p] = (w2[(c0+cc)*64 + jb+2p], ..+1) : j-pairs
  v2f w1p[4][3], mw1[4][3], vw1[4][3];
  #pragma unroll
  for (int m = 0; m < 4; ++m)
    #pragma unroll
    for (int p = 0; p < 3; ++p) {
      v2f t; t.x = mlp_w1[(jb + m) * 24 + c0 + 2 * p];
             t.y = mlp_w1[(jb + m) * 24 + c0 + 2 * p + 1];
      w1p[m][p] = t; mw1[m][p] = splat(0.f); vw1[m][p] = splat(0.f);
    }
  v2f w2p[6][2], mw2[6][2], vw2[6][2];
  #pragma unroll
  for (int cc = 0; cc < 6; ++cc)
    #pragma unroll
    for (int p = 0; p < 2; ++p) {
      v2f t; t.x = mlp_w2[(c0 + cc) * 64 + jb + 2 * p];
             t.y = mlp_w2[(c0 + cc) * 64 + jb + 2 * p + 1];
      w2p[cc][p] = t; mw2[cc][p] = splat(0.f); vw2[cc][p] = splat(0.f);
    }
  v2f b1p[3], mb1[3], vb1[3];
  #pragma unroll
  for (int p = 0; p < 3; ++p) {
    v2f t; t.x = mlp_b1[c0 + 2 * p] * flm; t.y = mlp_b1[c0 + 2 * p + 1] * flm;
    b1p[p] = t; mb1[p] = splat(0.f); vb1[p] = splat(0.f);
  }
  v2f b2p[2], mb2[2], vb2[2];
  #pragma unroll
  for (int p = 0; p < 2; ++p) {
    v2f t; t.x = mlp_b2[jb + 2 * p] * ugm; t.y = mlp_b2[jb + 2 * p + 1] * ugm;
    b2p[p] = t; mb2[p] = splat(0.f); vb2[p] = splat(0.f);
  }

  // rolling prefetch of (k,v) rows; v pre-scaled by 2/64
  float4 kf = *(const float4*)(enc + bka[0] * 64 + jb);
  float4 vf = *(const float4*)(enc + bva[0] * 64 + jb);
  float4 vs; vs.x = vf.x * S; vs.y = vf.y * S; vs.z = vf.z * S; vs.w = vf.w * S;

  #pragma unroll
  for (int step = 0; step < 8; ++step) {
    const int nidx = (step < 7) ? step + 1 : 7;
    float4 kfn = *(const float4*)(enc + bka[nidx] * 64 + jb);
    float4 vfn = *(const float4*)(enc + bva[nidx] * 64 + jb);

    const float lrrc1 = LRC * RC1T[step];
    const float rc2 = RC2T[step];
    const float km[4] = {kf.x, kf.y, kf.z, kf.w};

    // layer1: t2[p] = b1p[p] + sum_m k_m * w1p[m][p] (bias folded via flm mask)
    v2f t2[3] = {b1p[0], b1p[1], b1p[2]};
    #pragma unroll
    for (int m = 0; m < 4; ++m) {
      v2f km2 = splat(km[m]);
      #pragma unroll
      for (int p = 0; p < 3; ++p) t2[p] = __builtin_elementwise_fma(km2, w1p[m][p], t2[p]);
    }
    float t[6] = {t2[0].x, t2[0].y, t2[1].x, t2[1].y, t2[2].x, t2[2].y};
    row_sum_batch<6>(t);                          // row total at lane 15 of row
    #pragma unroll
    for (int cc = 0; cc < 6; ++cc) t[cc] = fmaxf(t[cc], 0.f);
    float asw[6];                                  // a, row-replicated (DS pipe)
    #pragma unroll
    for (int cc = 0; cc < 6; ++cc) asw[cc] = dswz<0x1F0>(t[cc]);

    // layer2 partials for own 4 j (bias folded via ugm mask)
    v2f po2[2] = {b2p[0], b2p[1]};
    #pragma unroll
    for (int cc = 0; cc < 6; ++cc) {
      v2f a2 = splat(asw[cc]);
      #pragma unroll
      for (int p = 0; p < 2; ++p) po2[p] = __builtin_elementwise_fma(a2, w2p[cc][p], po2[p]);
    }
    // cross-row butterfly sum (xor16 swizzle + xor32 bpermute) -> replicated
    float po[4] = {po2[0].x, po2[0].y, po2[1].x, po2[1].y};
    #pragma unroll
    for (int i = 0; i < 4; ++i) {
      po[i] += dswz<0x401F>(po[i]);
      po[i] += bperm(xaddr32, po[i]);
    }
    const float vsc[4] = {vs.x, vs.y, vs.z, vs.w};
    float dout[4];
    #pragma unroll
    for (int i = 0; i < 4; ++i) dout[i] = fmaf(po[i], S, -vsc[i]);
    v2f dout2[2]; dout2[0].x = dout[0]; dout2[0].y = dout[1];
                  dout2[1].x = dout[2]; dout2[1].y = dout[3];

    // dh[cc] = sum over own 4 j of w2*dout, then row-reduce + row-bcast + gate
    float dh[6];
    #pragma unroll
    for (int cc = 0; cc < 6; ++cc) {
      v2f q = w2p[cc][0] * dout2[0];
      q = __builtin_elementwise_fma(w2p[cc][1], dout2[1], q);
      dh[cc] = q.x + q.y;
    }
    row_sum_batch<6>(dh);
    float dpre[6];
    #pragma unroll
    for (int cc = 0; cc < 6; ++cc) {
      float dsw = dswz<0x1F0>(dh[cc]);
      dpre[cc] = (asw[cc] > 0.f) ? dsw : 0.f;     // relu' gate (a>0 <=> pre>0)
    }
    v2f dpre2[3]; dpre2[0].x = dpre[0]; dpre2[0].y = dpre[1];
                  dpre2[1].x = dpre[2]; dpre2[1].y = dpre[3];
                  dpre2[2].x = dpre[4]; dpre2[2].y = dpre[5];

    // Adam: w1 (g = k_j * dpre_c), w2 (g = a_c * dout_j), biases masked
    #pragma unroll
    for (int m = 0; m < 4; ++m) {
      v2f km2 = splat(km[m]);
      #pragma unroll
      for (int p = 0; p < 3; ++p)
        adam2(w1p[m][p], mw1[m][p], vw1[m][p], km2 * dpre2[p], lrrc1, rc2);
    }
    #pragma unroll
    for (int cc = 0; cc < 6; ++cc) {
      v2f a2 = splat(asw[cc]);
      #pragma unroll
      for (int p = 0; p < 2; ++p)
        adam2(w2p[cc][p], mw2[cc][p], vw2[cc][p], a2 * dout2[p], lrrc1, rc2);
    }
    #pragma unroll
    for (int p = 0; p < 3; ++p)
      adam2(b1p[p], mb1[p], vb1[p], dpre2[p] * splat(flm), lrrc1, rc2);
    #pragma unroll
    for (int p = 0; p < 2; ++p)
      adam2(b2p[p], mb2[p], vb2[p], dout2[p] * splat(ugm), lrrc1, rc2);

    kf = kfn;
    vs.x = vfn.x * S; vs.y = vfn.y * S; vs.z = vfn.z * S; vs.w = vfn.w * S;
  }

  // ---- query: enc[tok30] through finetuned MLP ----
  float4 qf = *(const float4*)(enc + q30 * 64 + jb);
  const float qm[4] = {qf.x, qf.y, qf.z, qf.w};
  v2f t2[3] = {b1p[0], b1p[1], b1p[2]};
  #pragma unroll
  for (int m = 0; m < 4; ++m) {
    v2f km2 = splat(qm[m]);
    #pragma unroll
    for (int p = 0; p < 3; ++p) t2[p] = __builtin_elementwise_fma(km2, w1p[m][p], t2[p]);
  }
  float t[6] = {t2[0].x, t2[0].y, t2[1].x, t2[1].y, t2[2].x, t2[2].y};
  row_sum_batch<6>(t);
  #pragma unroll
  for (int cc = 0; cc < 6; ++cc) t[cc] = fmaxf(t[cc], 0.f);
  float asw[6];
  #pragma unroll
  for (int cc = 0; cc < 6; ++cc) asw[cc] = dswz<0x1F0>(t[cc]);
  v2f po2[2] = {b2p[0], b2p[1]};
  #pragma unroll
  for (int cc = 0; cc < 6; ++cc) {
    v2f a2 = splat(asw[cc]);
    #pragma unroll
    for (int p = 0; p < 2; ++p) po2[p] = __builtin_elementwise_fma(a2, w2p[cc][p], po2[p]);
  }
  float po[4] = {po2[0].x, po2[0].y, po2[1].x, po2[1].y};
  #pragma unroll
  for (int i = 0; i < 4; ++i) {
    po[i] += dswz<0x401F>(po[i]);
    po[i] += bperm(xaddr32, po[i]);
  }
  // y_{4f+m} = po[m] @ lane f (rows replicated)

  // ---- output head: this lane computes output column v = lane ----
  float acc = out_b[lane];
  #pragma unroll
  for (int l = 0; l < 64; ++l) {
    float sy = rlane(po[l & 3], l >> 2);
    acc = fmaf(sy, out_w[l * 64 + lane], acc);
  }
  out[(size_t)sample * 64 + lane] = acc;
}

extern "C" void kernel_launch(void* const* d_in, const int* in_sizes, int n_in,
                              void* d_out, int out_size, void* d_ws, size_t ws_size,
                              hipStream_t stream) {
  const int*   seqs     = (const int*)d_in[0];
  const float* embed    = (const float*)d_in[1];
  const float* ff_w1    = (const float*)d_in[2];
  const float* ff_b1    = (const float*)d_in[3];
  const float* ff_w2    = (const float*)d_in[4];
  const float* ff_b2    = (const float*)d_in[5];
  const float* ln_g     = (const float*)d_in[6];
  const float* ln_b     = (const float*)d_in[7];
  const float* scorer_w = (const float*)d_in[8];
  const float* scorer_b = (const float*)d_in[9];
  const float* mlp_w1   = (const float*)d_in[10];
  const float* mlp_b1   = (const float*)d_in[11];
  const float* mlp_w2   = (const float*)d_in[12];
  const float* mlp_b2   = (const float*)d_in[13];
  const float* out_w    = (const float*)d_in[14];
  const float* out_b    = (const float*)d_in[15];

  const int B = in_sizes[0] / 32;        // 16384
  float* enc = (float*)d_ws;             // 64*64 floats = 16 KB
  float* sAt = enc + 64 * 64;            // 64 floats
  float* sBt = sAt + 64;                 // 64 floats

  enc_kernel<<<64, 64, 0, stream>>>(embed, ff_w1, ff_b1, ff_w2, ff_b2,
                                    ln_g, ln_b, scorer_w, enc, sAt, sBt);
  adam_kernel<<<B / 4, 256, 0, stream>>>(seqs, enc, sAt, sBt, scorer_b,
                                         mlp_w1, mlp_b1, mlp_w2, mlp_b2,
                                         out_w, out_b, (float*)d_out);
}

// Round 10
// 227.959 us; speedup vs baseline: 2.8992x; 1.0644x over previous
//
#include <hip/hip_runtime.h>

#define LRC   0.05f
#define B1C   0.9f
#define B2C   0.999f
#define C1C   0.1f      // float(1 - 0.9)
#define C2C   0.001f    // float(1 - 0.999)

typedef float v2f __attribute__((ext_vector_type(2)));

__device__ __forceinline__ v2f splat(float s) { v2f r; r.x = s; r.y = s; return r; }

__device__ __forceinline__ float rlane(float v, int l) {
  return __int_as_float(__builtin_amdgcn_readlane(__float_as_int(v), l));
}

template <int CTRL, int RMASK, bool BC>
__device__ __forceinline__ float dpp_add(float x) {
  int y = __builtin_amdgcn_update_dpp(0, __float_as_int(x), CTRL, RMASK, 0xF, BC);
  return x + __int_as_float(y);
}

template <int OFF>
__device__ __forceinline__ float dswz(float x) {
  return __int_as_float(__builtin_amdgcn_ds_swizzle(__float_as_int(x), OFF));
}
__device__ __forceinline__ float bperm(int addr, float x) {
  return __int_as_float(__builtin_amdgcn_ds_bpermute(addr, __float_as_int(x)));
}

// 4-stage 16-lane row prefix sum; row total lands in lanes 15/31/47/63
template <int N>
__device__ __forceinline__ void row_sum_batch(float* a) {
  #pragma unroll
  for (int c = 0; c < N; ++c) a[c] = dpp_add<0x111, 0xF, true>(a[c]);
  #pragma unroll
  for (int c = 0; c < N; ++c) a[c] = dpp_add<0x112, 0xF, true>(a[c]);
  #pragma unroll
  for (int c = 0; c < N; ++c) a[c] = dpp_add<0x114, 0xF, true>(a[c]);
  #pragma unroll
  for (int c = 0; c < N; ++c) a[c] = dpp_add<0x118, 0xF, true>(a[c]);
}

// full-wave sum replicated (enc_kernel only)
__device__ __forceinline__ float wave_sum_repl(float x) {
  x = dpp_add<0x111, 0xF, true>(x);
  x = dpp_add<0x112, 0xF, true>(x);
  x = dpp_add<0x114, 0xF, true>(x);
  x = dpp_add<0x118, 0xF, true>(x);
  x = dpp_add<0x142, 0xa, false>(x);
  x = dpp_add<0x143, 0xc, false>(x);
  return rlane(x, 63);
}

// ---------------- K1: encode table for the 64 distinct tokens ----------------
__global__ void enc_kernel(
    const float* __restrict__ embed,
    const float* __restrict__ ff_w1, const float* __restrict__ ff_b1,
    const float* __restrict__ ff_w2, const float* __restrict__ ff_b2,
    const float* __restrict__ ln_g, const float* __restrict__ ln_b,
    const float* __restrict__ scorer_w,
    float* __restrict__ enc, float* __restrict__ sAt, float* __restrict__ sBt)
{
  const int b = blockIdx.x;      // token id
  const int lane = threadIdx.x;  // feature

  float e = embed[b * 64 + lane];
  float acc0 = ff_b1[lane], acc1 = ff_b1[64 + lane];
  #pragma unroll
  for (int j = 0; j < 64; ++j) {
    float ej = rlane(e, j);
    acc0 = fmaf(ej, ff_w1[j * 128 + lane], acc0);
    acc1 = fmaf(ej, ff_w1[j * 128 + 64 + lane], acc1);
  }
  acc0 = fmaxf(acc0, 0.f);
  acc1 = fmaxf(acc1, 0.f);

  float f = ff_b2[lane];
  #pragma unroll
  for (int l = 0; l < 64; ++l) {
    f = fmaf(rlane(acc0, l), ff_w2[l * 64 + lane], f);
    f = fmaf(rlane(acc1, l), ff_w2[(l + 64) * 64 + lane], f);
  }

  float x = e + f;
  float mu = wave_sum_repl(x) * (1.f / 64.f);
  float d = x - mu;
  float var = wave_sum_repl(d * d) * (1.f / 64.f);
  float h = d * (1.f / sqrtf(var + 1e-5f)) * ln_g[lane] + ln_b[lane];
  enc[b * 64 + lane] = h;

  float sa = wave_sum_repl(h * scorer_w[lane]);
  float sb = wave_sum_repl(h * scorer_w[64 + lane]);
  if (lane == 0) { sAt[b] = sa; sBt[b] = sb; }
}

// ---------------- Adam, scaled-state form ----------------
// M = m/(1-b1), V = v/(1-b2). Update: p -= LRE[t] * M * rsqrt(V), where
// LRE[t] = lr*(1-b1)*rc1[t] / sqrt((1-b2)*rc2[t]) is a compile-time constant.
// 8 slot-ops per pair (vs 11 for the naive form), analytically identical.
__device__ __forceinline__ void adam2(v2f& p, v2f& M, v2f& V, v2f g, float lre) {
  M = __builtin_elementwise_fma(M, splat(B1C), g);
  V = __builtin_elementwise_fma(V, splat(B2C), g * g);
  v2f x = __builtin_elementwise_max(V, splat(1e-27f));
  v2f r; r.x = __builtin_amdgcn_rsqf(x.x);
         r.y = __builtin_amdgcn_rsqf(x.y);
  p = __builtin_elementwise_fma(M * r, splat(-lre), p);
}

// ---------------- K2: ONE wave per sample, 16 feat-lanes x 4 unit-rows ------
__global__ __launch_bounds__(256, 2) void adam_kernel(
    const int* __restrict__ seqs, const float* __restrict__ enc,
    const float* __restrict__ sAt, const float* __restrict__ sBt,
    const float* __restrict__ scorer_b,
    const float* __restrict__ mlp_w1, const float* __restrict__ mlp_b1,
    const float* __restrict__ mlp_w2, const float* __restrict__ mlp_b2,
    const float* __restrict__ out_w, const float* __restrict__ out_b,
    float* __restrict__ out)
{
  const int wid  = threadIdx.x >> 6;
  const int lane = threadIdx.x & 63;
  const int fl = lane & 15, ug = lane >> 4;
  const int c0 = 6 * ug, jb = 4 * fl;
  const int sample = blockIdx.x * 4 + wid;

  // LRE[t] = 0.005*rc1[t]/sqrt(0.001*rc2[t]), t=1..8
  constexpr float LRE[8] = {0.05f, 0.0372068f, 0.0319407f, 0.0290564f,
                            0.0272746f, 0.0261060f, 0.0253188f, 0.0247876f};

  int tv = seqs[sample * 32 + (lane & 31)];
  float sbv = scorer_b[0];

  // scores -> sortable uint keys (uniform; evict-min on SALU)
  unsigned skey[15]; int ta[15], tb[15];
  #pragma unroll
  for (int p = 0; p < 15; ++p) {
    ta[p] = __builtin_amdgcn_readfirstlane(__builtin_amdgcn_readlane(tv, 2 * p));
    tb[p] = __builtin_amdgcn_readfirstlane(__builtin_amdgcn_readlane(tv, 2 * p + 1));
    float s = sAt[ta[p]] + sBt[tb[p]] + sbv;
    unsigned u = __float_as_uint(s);
    unsigned k = u ^ (((unsigned)((int)u >> 31)) | 0x80000000u);
    skey[p] = __builtin_amdgcn_readfirstlane((int)k);
  }
  int q30 = __builtin_amdgcn_readfirstlane(__builtin_amdgcn_readlane(tv, 30));

  // evict-min; strict < keeps FIRST min
  unsigned bs[8]; int bka[8], bva[8];
  #pragma unroll
  for (int i = 0; i < 8; ++i) { bs[i] = skey[i]; bka[i] = ta[i]; bva[i] = tb[i]; }
  #pragma unroll
  for (int n = 0; n < 7; ++n) {
    int mi = 0; unsigned ms = bs[0];
    #pragma unroll
    for (int i = 1; i < 8; ++i) {
      if (bs[i] < ms) { mi = i; ms = bs[i]; }
    }
    #pragma unroll
    for (int i = 0; i < 7; ++i) {
      bool sh = i >= mi;
      bs[i]  = sh ? bs[i + 1]  : bs[i];
      bka[i] = sh ? bka[i + 1] : bka[i];
      bva[i] = sh ? bva[i + 1] : bva[i];
    }
    bs[7] = skey[8 + n]; bka[7] = ta[8 + n]; bva[7] = tb[8 + n];
  }

  const float flm = (fl == 0) ? 1.f : 0.f;   // bias-owner masks (exact 1/0)
  const float ugm = (ug == 0) ? 1.f : 0.f;
  // parallel cross-row rotate addresses (3 independent bpermutes, 1 DS latency)
  const int a16 = (((lane + 16) & 63) << 2);
  const int a32 = (((lane + 32) & 63) << 2);
  const int a48 = (((lane + 48) & 63) << 2);
  const float S = 2.f / 64.f;

  // ---- params ----
  v2f w1p[4][3], mw1[4][3], vw1[4][3];
  #pragma unroll
  for (int m = 0; m < 4; ++m)
    #pragma unroll
    for (int p = 0; p < 3; ++p) {
      v2f t; t.x = mlp_w1[(jb + m) * 24 + c0 + 2 * p];
             t.y = mlp_w1[(jb + m) * 24 + c0 + 2 * p + 1];
      w1p[m][p] = t; mw1[m][p] = splat(0.f); vw1[m][p] = splat(0.f);
    }
  v2f w2p[6][2], mw2[6][2], vw2[6][2];
  #pragma unroll
  for (int cc = 0; cc < 6; ++cc)
    #pragma unroll
    for (int p = 0; p < 2; ++p) {
      v2f t; t.x = mlp_w2[(c0 + cc) * 64 + jb + 2 * p];
             t.y = mlp_w2[(c0 + cc) * 64 + jb + 2 * p + 1];
      w2p[cc][p] = t; mw2[cc][p] = splat(0.f); vw2[cc][p] = splat(0.f);
    }
  v2f b1p[3], mb1[3], vb1[3];
  #pragma unroll
  for (int p = 0; p < 3; ++p) {
    v2f t; t.x = mlp_b1[c0 + 2 * p] * flm; t.y = mlp_b1[c0 + 2 * p + 1] * flm;
    b1p[p] = t; mb1[p] = splat(0.f); vb1[p] = splat(0.f);
  }
  v2f b2p[2], mb2[2], vb2[2];
  #pragma unroll
  for (int p = 0; p < 2; ++p) {
    v2f t; t.x = mlp_b2[jb + 2 * p] * ugm; t.y = mlp_b2[jb + 2 * p + 1] * ugm;
    b2p[p] = t; mb2[p] = splat(0.f); vb2[p] = splat(0.f);
  }

  // rolling prefetch of (k,v) rows; v pre-scaled by 2/64
  float4 kf = *(const float4*)(enc + bka[0] * 64 + jb);
  float4 vf = *(const float4*)(enc + bva[0] * 64 + jb);
  float4 vs; vs.x = vf.x * S; vs.y = vf.y * S; vs.z = vf.z * S; vs.w = vf.w * S;

  #pragma unroll
  for (int step = 0; step < 8; ++step) {
    const int nidx = (step < 7) ? step + 1 : 7;
    float4 kfn = *(const float4*)(enc + bka[nidx] * 64 + jb);
    float4 vfn = *(const float4*)(enc + bva[nidx] * 64 + jb);

    const float lre = LRE[step];
    const float km[4] = {kf.x, kf.y, kf.z, kf.w};

    // layer1: t2[p] = b1p[p] + sum_m k_m * w1p[m][p]
    v2f t2[3] = {b1p[0], b1p[1], b1p[2]};
    #pragma unroll
    for (int m = 0; m < 4; ++m) {
      v2f km2 = splat(km[m]);
      #pragma unroll
      for (int p = 0; p < 3; ++p) t2[p] = __builtin_elementwise_fma(km2, w1p[m][p], t2[p]);
    }
    float t[6] = {t2[0].x, t2[0].y, t2[1].x, t2[1].y, t2[2].x, t2[2].y};
    row_sum_batch<6>(t);
    #pragma unroll
    for (int cc = 0; cc < 6; ++cc) t[cc] = fmaxf(t[cc], 0.f);
    float asw[6];                                  // a, row-replicated
    #pragma unroll
    for (int cc = 0; cc < 6; ++cc) asw[cc] = dswz<0x1F0>(t[cc]);

    // layer2 partials for own 4 j
    v2f po2[2] = {b2p[0], b2p[1]};
    #pragma unroll
    for (int cc = 0; cc < 6; ++cc) {
      v2f a2 = splat(asw[cc]);
      #pragma unroll
      for (int p = 0; p < 2; ++p) po2[p] = __builtin_elementwise_fma(a2, w2p[cc][p], po2[p]);
    }
    // cross-row sum: 3 parallel bpermutes (one DS latency)
    float po[4] = {po2[0].x, po2[0].y, po2[1].x, po2[1].y};
    #pragma unroll
    for (int i = 0; i < 4; ++i) {
      float r1 = bperm(a16, po[i]);
      float r2 = bperm(a32, po[i]);
      float r3 = bperm(a48, po[i]);
      po[i] = ((po[i] + r1) + r2) + r3;
    }
    const float vsc[4] = {vs.x, vs.y, vs.z, vs.w};
    float dout[4];
    #pragma unroll
    for (int i = 0; i < 4; ++i) dout[i] = fmaf(po[i], S, -vsc[i]);
    v2f dout2[2]; dout2[0].x = dout[0]; dout2[0].y = dout[1];
                  dout2[1].x = dout[2]; dout2[1].y = dout[3];

    // dh[cc] over own 4 j, then row-reduce + row-bcast + relu' gate
    float dh[6];
    #pragma unroll
    for (int cc = 0; cc < 6; ++cc) {
      v2f q = w2p[cc][0] * dout2[0];
      q = __builtin_elementwise_fma(w2p[cc][1], dout2[1], q);
      dh[cc] = q.x + q.y;
    }
    row_sum_batch<6>(dh);
    float dpre[6];
    #pragma unroll
    for (int cc = 0; cc < 6; ++cc) {
      float dsw = dswz<0x1F0>(dh[cc]);
      dpre[cc] = (asw[cc] > 0.f) ? dsw : 0.f;
    }
    v2f dpre2[3]; dpre2[0].x = dpre[0]; dpre2[0].y = dpre[1];
                  dpre2[1].x = dpre[2]; dpre2[1].y = dpre[3];
                  dpre2[2].x = dpre[4]; dpre2[2].y = dpre[5];

    // Adam updates
    #pragma unroll
    for (int m = 0; m < 4; ++m) {
      v2f km2 = splat(km[m]);
      #pragma unroll
      for (int p = 0; p < 3; ++p)
        adam2(w1p[m][p], mw1[m][p], vw1[m][p], km2 * dpre2[p], lre);
    }
    #pragma unroll
    for (int cc = 0; cc < 6; ++cc) {
      v2f a2 = splat(asw[cc]);
      #pragma unroll
      for (int p = 0; p < 2; ++p)
        adam2(w2p[cc][p], mw2[cc][p], vw2[cc][p], a2 * dout2[p], lre);
    }
    #pragma unroll
    for (int p = 0; p < 3; ++p)
      adam2(b1p[p], mb1[p], vb1[p], dpre2[p] * splat(flm), lre);
    #pragma unroll
    for (int p = 0; p < 2; ++p)
      adam2(b2p[p], mb2[p], vb2[p], dout2[p] * splat(ugm), lre);

    kf = kfn;
    vs.x = vfn.x * S; vs.y = vfn.y * S; vs.z = vfn.z * S; vs.w = vfn.w * S;
  }

  // ---- query: enc[tok30] through finetuned MLP ----
  float4 qf = *(const float4*)(enc + q30 * 64 + jb);
  const float qm[4] = {qf.x, qf.y, qf.z, qf.w};
  v2f t2[3] = {b1p[0], b1p[1], b1p[2]};
  #pragma unroll
  for (int m = 0; m < 4; ++m) {
    v2f km2 = splat(qm[m]);
    #pragma unroll
    for (int p = 0; p < 3; ++p) t2[p] = __builtin_elementwise_fma(km2, w1p[m][p], t2[p]);
  }
  float t[6] = {t2[0].x, t2[0].y, t2[1].x, t2[1].y, t2[2].x, t2[2].y};
  row_sum_batch<6>(t);
  #pragma unroll
  for (int cc = 0; cc < 6; ++cc) t[cc] = fmaxf(t[cc], 0.f);
  float asw[6];
  #pragma unroll
  for (int cc = 0; cc < 6; ++cc) asw[cc] = dswz<0x1F0>(t[cc]);
  v2f po2[2] = {b2p[0], b2p[1]};
  #pragma unroll
  for (int cc = 0; cc < 6; ++cc) {
    v2f a2 = splat(asw[cc]);
    #pragma unroll
    for (int p = 0; p < 2; ++p) po2[p] = __builtin_elementwise_fma(a2, w2p[cc][p], po2[p]);
  }
  float po[4] = {po2[0].x, po2[0].y, po2[1].x, po2[1].y};
  #pragma unroll
  for (int i = 0; i < 4; ++i) {
    float r1 = bperm(a16, po[i]);
    float r2 = bperm(a32, po[i]);
    float r3 = bperm(a48, po[i]);
    po[i] = ((po[i] + r1) + r2) + r3;
  }
  // y_{4f+m} = po[m] @ lane f (replicated across rows)

  // ---- output head: this lane computes output column v = lane ----
  float acc = out_b[lane];
  #pragma unroll
  for (int l = 0; l < 64; ++l) {
    float sy = rlane(po[l & 3], l >> 2);
    acc = fmaf(sy, out_w[l * 64 + lane], acc);
  }
  out[(size_t)sample * 64 + lane] = acc;
}

extern "C" void kernel_launch(void* const* d_in, const int* in_sizes, int n_in,
                              void* d_out, int out_size, void* d_ws, size_t ws_size,
                              hipStream_t stream) {
  const int*   seqs     = (const int*)d_in[0];
  const float* embed    = (const float*)d_in[1];
  const float* ff_w1    = (const float*)d_in[2];
  const float* ff_b1    = (const float*)d_in[3];
  const float* ff_w2    = (const float*)d_in[4];
  const float* ff_b2    = (const float*)d_in[5];
  const float* ln_g     = (const float*)d_in[6];
  const float* ln_b     = (const float*)d_in[7];
  const float* scorer_w = (const float*)d_in[8];
  const float* scorer_b = (const float*)d_in[9];
  const float* mlp_w1   = (const float*)d_in[10];
  const float* mlp_b1   = (const float*)d_in[11];
  const float* mlp_w2   = (const float*)d_in[12];
  const float* mlp_b2   = (const float*)d_in[13];
  const float* out_w    = (const float*)d_in[14];
  const float* out_b    = (const float*)d_in[15];

  const int B = in_sizes[0] / 32;        // 16384
  float* enc = (float*)d_ws;             // 64*64 floats = 16 KB
  float* sAt = enc + 64 * 64;            // 64 floats
  float* sBt = sAt + 64;                 // 64 floats

  enc_kernel<<<64, 64, 0, stream>>>(embed, ff_w1, ff_b1, ff_w2, ff_b2,
                                    ln_g, ln_b, scorer_w, enc, sAt, sBt);
  adam_kernel<<<B / 4, 256, 0, stream>>>(seqs, enc, sAt, sBt, scorer_b,
                                         mlp_w1, mlp_b1, mlp_w2, mlp_b2,
                                         out_w, out_b, (float*)d_out);
}

// Round 11
// 215.703 us; speedup vs baseline: 3.0639x; 1.0568x over previous
//
#include <hip/hip_runtime.h>

#define LRC   0.05f
#define B1C   0.9f
#define B2C   0.999f

typedef float v2f __attribute__((ext_vector_type(2)));

__device__ __forceinline__ v2f splat(float s) { v2f r; r.x = s; r.y = s; return r; }

__device__ __forceinline__ float rlane(float v, int l) {
  return __int_as_float(__builtin_amdgcn_readlane(__float_as_int(v), l));
}

template <int CTRL, int RMASK, bool BC>
__device__ __forceinline__ float dpp_add(float x) {
  int y = __builtin_amdgcn_update_dpp(0, __float_as_int(x), CTRL, RMASK, 0xF, BC);
  return x + __int_as_float(y);
}

__device__ __forceinline__ float bperm(int addr, float x) {
  return __int_as_float(__builtin_amdgcn_ds_bpermute(addr, __float_as_int(x)));
}

// 4-stage 16-lane row reduction via row_ror: result REPLICATED in all 16 lanes
// (rotate-accumulate; no broadcast needed). 4 VALU per value, zero DS.
template <int N>
__device__ __forceinline__ void row_sum_batch(float* a) {
  #pragma unroll
  for (int c = 0; c < N; ++c) a[c] = dpp_add<0x121, 0xF, true>(a[c]);
  #pragma unroll
  for (int c = 0; c < N; ++c) a[c] = dpp_add<0x122, 0xF, true>(a[c]);
  #pragma unroll
  for (int c = 0; c < N; ++c) a[c] = dpp_add<0x124, 0xF, true>(a[c]);
  #pragma unroll
  for (int c = 0; c < N; ++c) a[c] = dpp_add<0x128, 0xF, true>(a[c]);
}

// full-wave sum replicated (enc_kernel only)
__device__ __forceinline__ float wave_sum_repl(float x) {
  x = dpp_add<0x111, 0xF, true>(x);
  x = dpp_add<0x112, 0xF, true>(x);
  x = dpp_add<0x114, 0xF, true>(x);
  x = dpp_add<0x118, 0xF, true>(x);
  x = dpp_add<0x142, 0xa, false>(x);
  x = dpp_add<0x143, 0xc, false>(x);
  return rlane(x, 63);
}

// ---------------- K1: encode table for the 64 distinct tokens ----------------
__global__ void enc_kernel(
    const float* __restrict__ embed,
    const float* __restrict__ ff_w1, const float* __restrict__ ff_b1,
    const float* __restrict__ ff_w2, const float* __restrict__ ff_b2,
    const float* __restrict__ ln_g, const float* __restrict__ ln_b,
    const float* __restrict__ scorer_w,
    float* __restrict__ enc, float* __restrict__ sAt, float* __restrict__ sBt)
{
  const int b = blockIdx.x;      // token id
  const int lane = threadIdx.x;  // feature

  float e = embed[b * 64 + lane];
  float acc0 = ff_b1[lane], acc1 = ff_b1[64 + lane];
  #pragma unroll
  for (int j = 0; j < 64; ++j) {
    float ej = rlane(e, j);
    acc0 = fmaf(ej, ff_w1[j * 128 + lane], acc0);
    acc1 = fmaf(ej, ff_w1[j * 128 + 64 + lane], acc1);
  }
  acc0 = fmaxf(acc0, 0.f);
  acc1 = fmaxf(acc1, 0.f);

  float f = ff_b2[lane];
  #pragma unroll
  for (int l = 0; l < 64; ++l) {
    f = fmaf(rlane(acc0, l), ff_w2[l * 64 + lane], f);
    f = fmaf(rlane(acc1, l), ff_w2[(l + 64) * 64 + lane], f);
  }

  float x = e + f;
  float mu = wave_sum_repl(x) * (1.f / 64.f);
  float d = x - mu;
  float var = wave_sum_repl(d * d) * (1.f / 64.f);
  float h = d * (1.f / sqrtf(var + 1e-5f)) * ln_g[lane] + ln_b[lane];
  enc[b * 64 + lane] = h;

  float sa = wave_sum_repl(h * scorer_w[lane]);
  float sb = wave_sum_repl(h * scorer_w[64 + lane]);
  if (lane == 0) { sAt[b] = sa; sBt[b] = sb; }
}

// ---------------- Adam, scaled-state form ----------------
// M = m/(1-b1), V = v/(1-b2); V initialized to 1e-27 (replaces the max-clamp:
// V >= 0.992e-27 through all 8 steps, so rsq never sees 0). 7 slot-ops/pair.
__device__ __forceinline__ void adam2(v2f& p, v2f& M, v2f& V, v2f g, float lre) {
  M = __builtin_elementwise_fma(M, splat(B1C), g);
  V = __builtin_elementwise_fma(V, splat(B2C), g * g);
  v2f r; r.x = __builtin_amdgcn_rsqf(V.x);
         r.y = __builtin_amdgcn_rsqf(V.y);
  p = __builtin_elementwise_fma(M * r, splat(-lre), p);
}

// ---------------- K2: ONE wave per sample, 16 feat-lanes x 4 unit-rows ------
__global__ __launch_bounds__(256, 2) void adam_kernel(
    const int* __restrict__ seqs, const float* __restrict__ enc,
    const float* __restrict__ sAt, const float* __restrict__ sBt,
    const float* __restrict__ scorer_b,
    const float* __restrict__ mlp_w1, const float* __restrict__ mlp_b1,
    const float* __restrict__ mlp_w2, const float* __restrict__ mlp_b2,
    const float* __restrict__ out_w, const float* __restrict__ out_b,
    float* __restrict__ out)
{
  const int wid  = threadIdx.x >> 6;
  const int lane = threadIdx.x & 63;
  const int fl = lane & 15, ug = lane >> 4;
  const int c0 = 6 * ug, jb = 4 * fl;
  const int sample = blockIdx.x * 4 + wid;

  // LRE[t] = 0.005*rc1[t]/sqrt(0.001*rc2[t]), t=1..8
  constexpr float LRE[8] = {0.05f, 0.0372068f, 0.0319407f, 0.0290564f,
                            0.0272746f, 0.0261060f, 0.0253188f, 0.0247876f};
  constexpr float VINIT = 1e-27f;

  int tv = seqs[sample * 32 + (lane & 31)];
  float sbv = scorer_b[0];

  // scores -> sortable uint keys (uniform; evict-min on SALU)
  unsigned skey[15]; int ta[15], tb[15];
  #pragma unroll
  for (int p = 0; p < 15; ++p) {
    ta[p] = __builtin_amdgcn_readfirstlane(__builtin_amdgcn_readlane(tv, 2 * p));
    tb[p] = __builtin_amdgcn_readfirstlane(__builtin_amdgcn_readlane(tv, 2 * p + 1));
    float s = sAt[ta[p]] + sBt[tb[p]] + sbv;
    unsigned u = __float_as_uint(s);
    unsigned k = u ^ (((unsigned)((int)u >> 31)) | 0x80000000u);
    skey[p] = __builtin_amdgcn_readfirstlane((int)k);
  }
  int q30 = __builtin_amdgcn_readfirstlane(__builtin_amdgcn_readlane(tv, 30));

  // evict-min; strict < keeps FIRST min
  unsigned bs[8]; int bka[8], bva[8];
  #pragma unroll
  for (int i = 0; i < 8; ++i) { bs[i] = skey[i]; bka[i] = ta[i]; bva[i] = tb[i]; }
  #pragma unroll
  for (int n = 0; n < 7; ++n) {
    int mi = 0; unsigned ms = bs[0];
    #pragma unroll
    for (int i = 1; i < 8; ++i) {
      if (bs[i] < ms) { mi = i; ms = bs[i]; }
    }
    #pragma unroll
    for (int i = 0; i < 7; ++i) {
      bool sh = i >= mi;
      bs[i]  = sh ? bs[i + 1]  : bs[i];
      bka[i] = sh ? bka[i + 1] : bka[i];
      bva[i] = sh ? bva[i + 1] : bva[i];
    }
    bs[7] = skey[8 + n]; bka[7] = ta[8 + n]; bva[7] = tb[8 + n];
  }

  const float flm = (fl == 0) ? 1.f : 0.f;   // bias-owner masks (exact 1/0)
  const float ugm = (ug == 0) ? 1.f : 0.f;
  // parallel cross-row rotate addresses (3 independent bpermutes, 1 DS latency)
  const int a16 = (((lane + 16) & 63) << 2);
  const int a32 = (((lane + 32) & 63) << 2);
  const int a48 = (((lane + 48) & 63) << 2);
  const float S = 2.f / 64.f;

  // ---- params ----
  v2f w1p[4][3], mw1[4][3], vw1[4][3];
  #pragma unroll
  for (int m = 0; m < 4; ++m)
    #pragma unroll
    for (int p = 0; p < 3; ++p) {
      v2f t; t.x = mlp_w1[(jb + m) * 24 + c0 + 2 * p];
             t.y = mlp_w1[(jb + m) * 24 + c0 + 2 * p + 1];
      w1p[m][p] = t; mw1[m][p] = splat(0.f); vw1[m][p] = splat(VINIT);
    }
  v2f w2p[6][2], mw2[6][2], vw2[6][2];
  #pragma unroll
  for (int cc = 0; cc < 6; ++cc)
    #pragma unroll
    for (int p = 0; p < 2; ++p) {
      v2f t; t.x = mlp_w2[(c0 + cc) * 64 + jb + 2 * p];
             t.y = mlp_w2[(c0 + cc) * 64 + jb + 2 * p + 1];
      w2p[cc][p] = t; mw2[cc][p] = splat(0.f); vw2[cc][p] = splat(VINIT);
    }
  v2f b1p[3], mb1[3], vb1[3];
  #pragma unroll
  for (int p = 0; p < 3; ++p) {
    v2f t; t.x = mlp_b1[c0 + 2 * p] * flm; t.y = mlp_b1[c0 + 2 * p + 1] * flm;
    b1p[p] = t; mb1[p] = splat(0.f); vb1[p] = splat(VINIT);
  }
  v2f b2p[2], mb2[2], vb2[2];
  #pragma unroll
  for (int p = 0; p < 2; ++p) {
    v2f t; t.x = mlp_b2[jb + 2 * p] * ugm; t.y = mlp_b2[jb + 2 * p + 1] * ugm;
    b2p[p] = t; mb2[p] = splat(0.f); vb2[p] = splat(VINIT);
  }

  // rolling prefetch of (k,v) rows; v pre-scaled by 2/64
  float4 kf = *(const float4*)(enc + bka[0] * 64 + jb);
  float4 vf = *(const float4*)(enc + bva[0] * 64 + jb);
  float4 vs; vs.x = vf.x * S; vs.y = vf.y * S; vs.z = vf.z * S; vs.w = vf.w * S;

  #pragma unroll
  for (int step = 0; step < 8; ++step) {
    const int nidx = (step < 7) ? step + 1 : 7;
    float4 kfn = *(const float4*)(enc + bka[nidx] * 64 + jb);
    float4 vfn = *(const float4*)(enc + bva[nidx] * 64 + jb);

    const float lre = LRE[step];
    const float km[4] = {kf.x, kf.y, kf.z, kf.w};

    // layer1: t2[p] = b1p[p] + sum_m k_m * w1p[m][p]
    v2f t2[3] = {b1p[0], b1p[1], b1p[2]};
    #pragma unroll
    for (int m = 0; m < 4; ++m) {
      v2f km2 = splat(km[m]);
      #pragma unroll
      for (int p = 0; p < 3; ++p) t2[p] = __builtin_elementwise_fma(km2, w1p[m][p], t2[p]);
    }
    float t[6] = {t2[0].x, t2[0].y, t2[1].x, t2[1].y, t2[2].x, t2[2].y};
    row_sum_batch<6>(t);                          // replicated in all row lanes
    float asw[6];
    #pragma unroll
    for (int cc = 0; cc < 6; ++cc) asw[cc] = fmaxf(t[cc], 0.f);

    // layer2 partials for own 4 j
    v2f po2[2] = {b2p[0], b2p[1]};
    #pragma unroll
    for (int cc = 0; cc < 6; ++cc) {
      v2f a2 = splat(asw[cc]);
      #pragma unroll
      for (int p = 0; p < 2; ++p) po2[p] = __builtin_elementwise_fma(a2, w2p[cc][p], po2[p]);
    }
    // cross-row sum: 3 parallel bpermutes (one DS latency)
    float po[4] = {po2[0].x, po2[0].y, po2[1].x, po2[1].y};
    #pragma unroll
    for (int i = 0; i < 4; ++i) {
      float r1 = bperm(a16, po[i]);
      float r2 = bperm(a32, po[i]);
      float r3 = bperm(a48, po[i]);
      po[i] = ((po[i] + r1) + r2) + r3;
    }
    const float vsc[4] = {vs.x, vs.y, vs.z, vs.w};
    float dout[4];
    #pragma unroll
    for (int i = 0; i < 4; ++i) dout[i] = fmaf(po[i], S, -vsc[i]);
    v2f dout2[2]; dout2[0].x = dout[0]; dout2[0].y = dout[1];
                  dout2[1].x = dout[2]; dout2[1].y = dout[3];

    // dh[cc] over own 4 j, then row-reduce (replicated) + relu' gate
    float dh[6];
    #pragma unroll
    for (int cc = 0; cc < 6; ++cc) {
      v2f q = w2p[cc][0] * dout2[0];
      q = __builtin_elementwise_fma(w2p[cc][1], dout2[1], q);
      dh[cc] = q.x + q.y;
    }
    row_sum_batch<6>(dh);
    float dpre[6];
    #pragma unroll
    for (int cc = 0; cc < 6; ++cc)
      dpre[cc] = (asw[cc] > 0.f) ? dh[cc] : 0.f;
    v2f dpre2[3]; dpre2[0].x = dpre[0]; dpre2[0].y = dpre[1];
                  dpre2[1].x = dpre[2]; dpre2[1].y = dpre[3];
                  dpre2[2].x = dpre[4]; dpre2[2].y = dpre[5];

    // Adam updates
    #pragma unroll
    for (int m = 0; m < 4; ++m) {
      v2f km2 = splat(km[m]);
      #pragma unroll
      for (int p = 0; p < 3; ++p)
        adam2(w1p[m][p], mw1[m][p], vw1[m][p], km2 * dpre2[p], lre);
    }
    #pragma unroll
    for (int cc = 0; cc < 6; ++cc) {
      v2f a2 = splat(asw[cc]);
      #pragma unroll
      for (int p = 0; p < 2; ++p)
        adam2(w2p[cc][p], mw2[cc][p], vw2[cc][p], a2 * dout2[p], lre);
    }
    #pragma unroll
    for (int p = 0; p < 3; ++p)
      adam2(b1p[p], mb1[p], vb1[p], dpre2[p] * splat(flm), lre);
    #pragma unroll
    for (int p = 0; p < 2; ++p)
      adam2(b2p[p], mb2[p], vb2[p], dout2[p] * splat(ugm), lre);

    kf = kfn;
    vs.x = vfn.x * S; vs.y = vfn.y * S; vs.z = vfn.z * S; vs.w = vfn.w * S;
  }

  // ---- query: enc[tok30] through finetuned MLP ----
  float4 qf = *(const float4*)(enc + q30 * 64 + jb);
  const float qm[4] = {qf.x, qf.y, qf.z, qf.w};
  v2f t2[3] = {b1p[0], b1p[1], b1p[2]};
  #pragma unroll
  for (int m = 0; m < 4; ++m) {
    v2f km2 = splat(qm[m]);
    #pragma unroll
    for (int p = 0; p < 3; ++p) t2[p] = __builtin_elementwise_fma(km2, w1p[m][p], t2[p]);
  }
  float t[6] = {t2[0].x, t2[0].y, t2[1].x, t2[1].y, t2[2].x, t2[2].y};
  row_sum_batch<6>(t);
  float asw[6];
  #pragma unroll
  for (int cc = 0; cc < 6; ++cc) asw[cc] = fmaxf(t[cc], 0.f);
  v2f po2[2] = {b2p[0], b2p[1]};
  #pragma unroll
  for (int cc = 0; cc < 6; ++cc) {
    v2f a2 = splat(asw[cc]);
    #pragma unroll
    for (int p = 0; p < 2; ++p) po2[p] = __builtin_elementwise_fma(a2, w2p[cc][p], po2[p]);
  }
  float po[4] = {po2[0].x, po2[0].y, po2[1].x, po2[1].y};
  #pragma unroll
  for (int i = 0; i < 4; ++i) {
    float r1 = bperm(a16, po[i]);
    float r2 = bperm(a32, po[i]);
    float r3 = bperm(a48, po[i]);
    po[i] = ((po[i] + r1) + r2) + r3;
  }
  // y_{4f+m} = po[m] @ lane f (replicated across rows)

  // ---- output head: this lane computes output column v = lane ----
  float acc = out_b[lane];
  #pragma unroll
  for (int l = 0; l < 64; ++l) {
    float sy = rlane(po[l & 3], l >> 2);
    acc = fmaf(sy, out_w[l * 64 + lane], acc);
  }
  out[(size_t)sample * 64 + lane] = acc;
}

extern "C" void kernel_launch(void* const* d_in, const int* in_sizes, int n_in,
                              void* d_out, int out_size, void* d_ws, size_t ws_size,
                              hipStream_t stream) {
  const int*   seqs     = (const int*)d_in[0];
  const float* embed    = (const float*)d_in[1];
  const float* ff_w1    = (const float*)d_in[2];
  const float* ff_b1    = (const float*)d_in[3];
  const float* ff_w2    = (const float*)d_in[4];
  const float* ff_b2    = (const float*)d_in[5];
  const float* ln_g     = (const float*)d_in[6];
  const float* ln_b     = (const float*)d_in[7];
  const float* scorer_w = (const float*)d_in[8];
  const float* scorer_b = (const float*)d_in[9];
  const float* mlp_w1   = (const float*)d_in[10];
  const float* mlp_b1   = (const float*)d_in[11];
  const float* mlp_w2   = (const float*)d_in[12];
  const float* mlp_b2   = (const float*)d_in[13];
  const float* out_w    = (const float*)d_in[14];
  const float* out_b    = (const float*)d_in[15];

  const int B = in_sizes[0] / 32;        // 16384
  float* enc = (float*)d_ws;             // 64*64 floats = 16 KB
  float* sAt = enc + 64 * 64;            // 64 floats
  float* sBt = sAt + 64;                 // 64 floats

  enc_kernel<<<64, 64, 0, stream>>>(embed, ff_w1, ff_b1, ff_w2, ff_b2,
                                    ln_g, ln_b, scorer_w, enc, sAt, sBt);
  adam_kernel<<<B / 4, 256, 0, stream>>>(seqs, enc, sAt, sBt, scorer_b,
                                         mlp_w1, mlp_b1, mlp_w2, mlp_b2,
                                         out_w, out_b, (float*)d_out);
}

// Round 12
// 209.258 us; speedup vs baseline: 3.1583x; 1.0308x over previous
//
#include <hip/hip_runtime.h>

#define LRC   0.05f
#define B1C   0.9f
#define B2C   0.999f

typedef float v2f __attribute__((ext_vector_type(2)));

__device__ __forceinline__ v2f splat(float s) { v2f r; r.x = s; r.y = s; return r; }

__device__ __forceinline__ float rlane(float v, int l) {
  return __int_as_float(__builtin_amdgcn_readlane(__float_as_int(v), l));
}

template <int CTRL, int RMASK, bool BC>
__device__ __forceinline__ float dpp_add(float x) {
  int y = __builtin_amdgcn_update_dpp(0, __float_as_int(x), CTRL, RMASK, 0xF, BC);
  return x + __int_as_float(y);
}

__device__ __forceinline__ float bperm(int addr, float x) {
  return __int_as_float(__builtin_amdgcn_ds_bpermute(addr, __float_as_int(x)));
}

// 4-stage 16-lane row reduction via row_ror: result REPLICATED in all 16 lanes
template <int N>
__device__ __forceinline__ void row_sum_batch(float* a) {
  #pragma unroll
  for (int c = 0; c < N; ++c) a[c] = dpp_add<0x121, 0xF, true>(a[c]);
  #pragma unroll
  for (int c = 0; c < N; ++c) a[c] = dpp_add<0x122, 0xF, true>(a[c]);
  #pragma unroll
  for (int c = 0; c < N; ++c) a[c] = dpp_add<0x124, 0xF, true>(a[c]);
  #pragma unroll
  for (int c = 0; c < N; ++c) a[c] = dpp_add<0x128, 0xF, true>(a[c]);
}

// full-wave sum replicated (enc_kernel only)
__device__ __forceinline__ float wave_sum_repl(float x) {
  x = dpp_add<0x111, 0xF, true>(x);
  x = dpp_add<0x112, 0xF, true>(x);
  x = dpp_add<0x114, 0xF, true>(x);
  x = dpp_add<0x118, 0xF, true>(x);
  x = dpp_add<0x142, 0xa, false>(x);
  x = dpp_add<0x143, 0xc, false>(x);
  return rlane(x, 63);
}

// ---------------- K1: encode table for the 64 distinct tokens ----------------
__global__ void enc_kernel(
    const float* __restrict__ embed,
    const float* __restrict__ ff_w1, const float* __restrict__ ff_b1,
    const float* __restrict__ ff_w2, const float* __restrict__ ff_b2,
    const float* __restrict__ ln_g, const float* __restrict__ ln_b,
    const float* __restrict__ scorer_w,
    float* __restrict__ enc, float* __restrict__ sAt, float* __restrict__ sBt)
{
  const int b = blockIdx.x;      // token id
  const int lane = threadIdx.x;  // feature

  float e = embed[b * 64 + lane];
  float acc0 = ff_b1[lane], acc1 = ff_b1[64 + lane];
  #pragma unroll
  for (int j = 0; j < 64; ++j) {
    float ej = rlane(e, j);
    acc0 = fmaf(ej, ff_w1[j * 128 + lane], acc0);
    acc1 = fmaf(ej, ff_w1[j * 128 + 64 + lane], acc1);
  }
  acc0 = fmaxf(acc0, 0.f);
  acc1 = fmaxf(acc1, 0.f);

  float f = ff_b2[lane];
  #pragma unroll
  for (int l = 0; l < 64; ++l) {
    f = fmaf(rlane(acc0, l), ff_w2[l * 64 + lane], f);
    f = fmaf(rlane(acc1, l), ff_w2[(l + 64) * 64 + lane], f);
  }

  float x = e + f;
  float mu = wave_sum_repl(x) * (1.f / 64.f);
  float d = x - mu;
  float var = wave_sum_repl(d * d) * (1.f / 64.f);
  float h = d * (1.f / sqrtf(var + 1e-5f)) * ln_g[lane] + ln_b[lane];
  enc[b * 64 + lane] = h;

  float sa = wave_sum_repl(h * scorer_w[lane]);
  float sb = wave_sum_repl(h * scorer_w[64 + lane]);
  if (lane == 0) { sAt[b] = sa; sBt[b] = sb; }
}

// ---------------- Adam, scaled-state form ----------------
// M = m/(1-b1), V = v/(1-b2); V init 1e-27 replaces the eps/clamp.
__device__ __forceinline__ void adam2(v2f& p, v2f& M, v2f& V, v2f g, float lre) {
  M = __builtin_elementwise_fma(M, splat(B1C), g);
  V = __builtin_elementwise_fma(V, splat(B2C), g * g);
  v2f r; r.x = __builtin_amdgcn_rsqf(V.x);
         r.y = __builtin_amdgcn_rsqf(V.y);
  p = __builtin_elementwise_fma(M * r, splat(-lre), p);
}

// ---------------- K2: ONE wave per sample, 16 feat-lanes x 4 unit-rows ------
__global__ __launch_bounds__(256, 2) void adam_kernel(
    const int* __restrict__ seqs, const float* __restrict__ enc,
    const float* __restrict__ sAt, const float* __restrict__ sBt,
    const float* __restrict__ mlp_w1, const float* __restrict__ mlp_b1,
    const float* __restrict__ mlp_w2, const float* __restrict__ mlp_b2,
    const float* __restrict__ out_w, const float* __restrict__ out_b,
    float* __restrict__ out)
{
  const int wid  = threadIdx.x >> 6;
  const int lane = threadIdx.x & 63;
  const int fl = lane & 15, ug = lane >> 4;
  const int c0 = 6 * ug, jb = 4 * fl;
  const int sample = blockIdx.x * 4 + wid;

  // LRE[t] = 0.005*rc1[t]/sqrt(0.001*rc2[t]), t=1..8
  constexpr float LRE[8] = {0.05f, 0.0372068f, 0.0319407f, 0.0290564f,
                            0.0272746f, 0.0261060f, 0.0253188f, 0.0247876f};
  constexpr float VINIT = 1e-27f;

  int tv = seqs[sample * 32 + (lane & 31)];

  // scores -> sortable uint keys. scorer_b dropped: a uniform additive
  // constant cannot change argmin order (monotone key map). Key bit-twiddle
  // done on SALU after readfirstlane.
  unsigned skey[15]; int ta[15], tb[15];
  #pragma unroll
  for (int p = 0; p < 15; ++p) {
    ta[p] = __builtin_amdgcn_readlane(tv, 2 * p);
    tb[p] = __builtin_amdgcn_readlane(tv, 2 * p + 1);
    float sf = sAt[ta[p]] + sBt[tb[p]];
    int si = __builtin_amdgcn_readfirstlane(__float_as_int(sf));
    unsigned u = (unsigned)si;
    skey[p] = u ^ (((unsigned)(si >> 31)) | 0x80000000u);
  }
  int q30 = __builtin_amdgcn_readlane(tv, 30);

  // evict-min; strict < keeps FIRST min (all SALU)
  unsigned bs[8]; int bka[8], bva[8];
  #pragma unroll
  for (int i = 0; i < 8; ++i) { bs[i] = skey[i]; bka[i] = ta[i]; bva[i] = tb[i]; }
  #pragma unroll
  for (int n = 0; n < 7; ++n) {
    int mi = 0; unsigned ms = bs[0];
    #pragma unroll
    for (int i = 1; i < 8; ++i) {
      if (bs[i] < ms) { mi = i; ms = bs[i]; }
    }
    #pragma unroll
    for (int i = 0; i < 7; ++i) {
      bool sh = i >= mi;
      bs[i]  = sh ? bs[i + 1]  : bs[i];
      bka[i] = sh ? bka[i + 1] : bka[i];
      bva[i] = sh ? bva[i + 1] : bva[i];
    }
    bs[7] = skey[8 + n]; bka[7] = ta[8 + n]; bva[7] = tb[8 + n];
  }

  const float flm = (fl == 0) ? 1.f : 0.f;   // bias-owner masks
  const float ugm = (ug == 0) ? 1.f : 0.f;
  const int a16 = (((lane + 16) & 63) << 2);
  const int a32 = (((lane + 32) & 63) << 2);
  const int a48 = (((lane + 48) & 63) << 2);
  const float S = 2.f / 64.f;

  // ---- params: direct float2 (v2f) loads — all pairs are even-offset ----
  v2f w1p[4][3], mw1[4][3], vw1[4][3];
  #pragma unroll
  for (int m = 0; m < 4; ++m) {
    const v2f* src = (const v2f*)(mlp_w1 + (jb + m) * 24 + c0);
    #pragma unroll
    for (int p = 0; p < 3; ++p) {
      w1p[m][p] = src[p]; mw1[m][p] = splat(0.f); vw1[m][p] = splat(VINIT);
    }
  }
  v2f w2p[6][2], mw2[6][2], vw2[6][2];
  #pragma unroll
  for (int cc = 0; cc < 6; ++cc) {
    const v2f* src = (const v2f*)(mlp_w2 + (c0 + cc) * 64 + jb);
    #pragma unroll
    for (int p = 0; p < 2; ++p) {
      w2p[cc][p] = src[p]; mw2[cc][p] = splat(0.f); vw2[cc][p] = splat(VINIT);
    }
  }
  v2f b1p[3], mb1[3], vb1[3];
  {
    const v2f* src = (const v2f*)(mlp_b1 + c0);
    #pragma unroll
    for (int p = 0; p < 3; ++p) {
      b1p[p] = src[p] * splat(flm); mb1[p] = splat(0.f); vb1[p] = splat(VINIT);
    }
  }
  v2f b2p[2], mb2[2], vb2[2];
  {
    const v2f* src = (const v2f*)(mlp_b2 + jb);
    #pragma unroll
    for (int p = 0; p < 2; ++p) {
      b2p[p] = src[p] * splat(ugm); mb2[p] = splat(0.f); vb2[p] = splat(VINIT);
    }
  }

  // rolling prefetch of (k,v) rows; v pre-scaled by -S (so dout = fma(po,S,vn))
  float4 kf = *(const float4*)(enc + bka[0] * 64 + jb);
  float4 vf = *(const float4*)(enc + bva[0] * 64 + jb);
  v2f vn[2];
  vn[0].x = vf.x * -S; vn[0].y = vf.y * -S;
  vn[1].x = vf.z * -S; vn[1].y = vf.w * -S;

  #pragma unroll
  for (int step = 0; step < 8; ++step) {
    const int nidx = (step < 7) ? step + 1 : 7;
    float4 kfn = *(const float4*)(enc + bka[nidx] * 64 + jb);
    float4 vfn = *(const float4*)(enc + bva[nidx] * 64 + jb);

    const float lre = LRE[step];
    const float km[4] = {kf.x, kf.y, kf.z, kf.w};

    // layer1: t2[p] = b1p[p] + sum_m k_m * w1p[m][p]
    v2f t2[3] = {b1p[0], b1p[1], b1p[2]};
    #pragma unroll
    for (int m = 0; m < 4; ++m) {
      v2f km2 = splat(km[m]);
      #pragma unroll
      for (int p = 0; p < 3; ++p) t2[p] = __builtin_elementwise_fma(km2, w1p[m][p], t2[p]);
    }
    float t[6] = {t2[0].x, t2[0].y, t2[1].x, t2[1].y, t2[2].x, t2[2].y};
    row_sum_batch<6>(t);                          // replicated in all row lanes
    float asw[6];
    #pragma unroll
    for (int cc = 0; cc < 6; ++cc) asw[cc] = fmaxf(t[cc], 0.f);

    // layer2 partials (2-branch tree to halve the dependency chain)
    v2f po2[2];
    #pragma unroll
    for (int p = 0; p < 2; ++p) {
      v2f e0 = b2p[p], e1 = splat(asw[3]) * w2p[3][p];
      e0 = __builtin_elementwise_fma(splat(asw[0]), w2p[0][p], e0);
      e1 = __builtin_elementwise_fma(splat(asw[4]), w2p[4][p], e1);
      e0 = __builtin_elementwise_fma(splat(asw[1]), w2p[1][p], e0);
      e1 = __builtin_elementwise_fma(splat(asw[5]), w2p[5][p], e1);
      e0 = __builtin_elementwise_fma(splat(asw[2]), w2p[2][p], e0);
      po2[p] = e0 + e1;
    }
    // cross-row sum: 3 parallel bpermutes per component, packed adds
    #pragma unroll
    for (int p = 0; p < 2; ++p) {
      v2f r16, r32, r48;
      r16.x = bperm(a16, po2[p].x); r16.y = bperm(a16, po2[p].y);
      r32.x = bperm(a32, po2[p].x); r32.y = bperm(a32, po2[p].y);
      r48.x = bperm(a48, po2[p].x); r48.y = bperm(a48, po2[p].y);
      po2[p] = ((po2[p] + r16) + (r32 + r48));
    }
    v2f dout2[2];
    #pragma unroll
    for (int p = 0; p < 2; ++p)
      dout2[p] = __builtin_elementwise_fma(po2[p], splat(S), vn[p]);

    // dh[cc] over own 4 j, then row-reduce (replicated) + relu' gate
    float dh[6];
    #pragma unroll
    for (int cc = 0; cc < 6; ++cc) {
      v2f q = w2p[cc][0] * dout2[0];
      q = __builtin_elementwise_fma(w2p[cc][1], dout2[1], q);
      dh[cc] = q.x + q.y;
    }
    row_sum_batch<6>(dh);
    float dpre[6];
    #pragma unroll
    for (int cc = 0; cc < 6; ++cc)
      dpre[cc] = (asw[cc] > 0.f) ? dh[cc] : 0.f;
    v2f dpre2[3]; dpre2[0].x = dpre[0]; dpre2[0].y = dpre[1];
                  dpre2[1].x = dpre[2]; dpre2[1].y = dpre[3];
                  dpre2[2].x = dpre[4]; dpre2[2].y = dpre[5];

    // Adam updates
    #pragma unroll
    for (int m = 0; m < 4; ++m) {
      v2f km2 = splat(km[m]);
      #pragma unroll
      for (int p = 0; p < 3; ++p)
        adam2(w1p[m][p], mw1[m][p], vw1[m][p], km2 * dpre2[p], lre);
    }
    #pragma unroll
    for (int cc = 0; cc < 6; ++cc) {
      v2f a2 = splat(asw[cc]);
      #pragma unroll
      for (int p = 0; p < 2; ++p)
        adam2(w2p[cc][p], mw2[cc][p], vw2[cc][p], a2 * dout2[p], lre);
    }
    #pragma unroll
    for (int p = 0; p < 3; ++p)
      adam2(b1p[p], mb1[p], vb1[p], dpre2[p] * splat(flm), lre);
    #pragma unroll
    for (int p = 0; p < 2; ++p)
      adam2(b2p[p], mb2[p], vb2[p], dout2[p] * splat(ugm), lre);

    kf = kfn;
    vn[0].x = vfn.x * -S; vn[0].y = vfn.y * -S;
    vn[1].x = vfn.z * -S; vn[1].y = vfn.w * -S;
  }

  // ---- query: enc[tok30] through finetuned MLP ----
  float4 qf = *(const float4*)(enc + q30 * 64 + jb);
  const float qm[4] = {qf.x, qf.y, qf.z, qf.w};
  v2f t2[3] = {b1p[0], b1p[1], b1p[2]};
  #pragma unroll
  for (int m = 0; m < 4; ++m) {
    v2f km2 = splat(qm[m]);
    #pragma unroll
    for (int p = 0; p < 3; ++p) t2[p] = __builtin_elementwise_fma(km2, w1p[m][p], t2[p]);
  }
  float t[6] = {t2[0].x, t2[0].y, t2[1].x, t2[1].y, t2[2].x, t2[2].y};
  row_sum_batch<6>(t);
  float asw[6];
  #pragma unroll
  for (int cc = 0; cc < 6; ++cc) asw[cc] = fmaxf(t[cc], 0.f);
  v2f po2[2];
  #pragma unroll
  for (int p = 0; p < 2; ++p) {
    v2f e0 = b2p[p], e1 = splat(asw[3]) * w2p[3][p];
    e0 = __builtin_elementwise_fma(splat(asw[0]), w2p[0][p], e0);
    e1 = __builtin_elementwise_fma(splat(asw[4]), w2p[4][p], e1);
    e0 = __builtin_elementwise_fma(splat(asw[1]), w2p[1][p], e0);
    e1 = __builtin_elementwise_fma(splat(asw[5]), w2p[5][p], e1);
    e0 = __builtin_elementwise_fma(splat(asw[2]), w2p[2][p], e0);
    po2[p] = e0 + e1;
  }
  #pragma unroll
  for (int p = 0; p < 2; ++p) {
    v2f r16, r32, r48;
    r16.x = bperm(a16, po2[p].x); r16.y = bperm(a16, po2[p].y);
    r32.x = bperm(a32, po2[p].x); r32.y = bperm(a32, po2[p].y);
    r48.x = bperm(a48, po2[p].x); r48.y = bperm(a48, po2[p].y);
    po2[p] = ((po2[p] + r16) + (r32 + r48));
  }
  float po[4] = {po2[0].x, po2[0].y, po2[1].x, po2[1].y};
  // y_{4f+m} = po[m] @ lane f (replicated across rows)

  // ---- output head: lane = output column; 4 accumulators to cut the chain ----
  float ac0 = out_b[lane], ac1 = 0.f, ac2 = 0.f, ac3 = 0.f;
  #pragma unroll
  for (int l = 0; l < 64; l += 4) {
    ac0 = fmaf(rlane(po[0], l >> 2), out_w[(l    ) * 64 + lane], ac0);
    ac1 = fmaf(rlane(po[1], l >> 2), out_w[(l + 1) * 64 + lane], ac1);
    ac2 = fmaf(rlane(po[2], l >> 2), out_w[(l + 2) * 64 + lane], ac2);
    ac3 = fmaf(rlane(po[3], l >> 2), out_w[(l + 3) * 64 + lane], ac3);
  }
  out[(size_t)sample * 64 + lane] = (ac0 + ac1) + (ac2 + ac3);
}

extern "C" void kernel_launch(void* const* d_in, const int* in_sizes, int n_in,
                              void* d_out, int out_size, void* d_ws, size_t ws_size,
                              hipStream_t stream) {
  const int*   seqs     = (const int*)d_in[0];
  const float* embed    = (const float*)d_in[1];
  const float* ff_w1    = (const float*)d_in[2];
  const float* ff_b1    = (const float*)d_in[3];
  const float* ff_w2    = (const float*)d_in[4];
  const float* ff_b2    = (const float*)d_in[5];
  const float* ln_g     = (const float*)d_in[6];
  const float* ln_b     = (const float*)d_in[7];
  const float* scorer_w = (const float*)d_in[8];
  const float* mlp_w1   = (const float*)d_in[10];
  const float* mlp_b1   = (const float*)d_in[11];
  const float* mlp_w2   = (const float*)d_in[12];
  const float* mlp_b2   = (const float*)d_in[13];
  const float* out_w    = (const float*)d_in[14];
  const float* out_b    = (const float*)d_in[15];

  const int B = in_sizes[0] / 32;        // 16384
  float* enc = (float*)d_ws;             // 64*64 floats = 16 KB
  float* sAt = enc + 64 * 64;            // 64 floats
  float* sBt = sAt + 64;                 // 64 floats

  enc_kernel<<<64, 64, 0, stream>>>(embed, ff_w1, ff_b1, ff_w2, ff_b2,
                                    ln_g, ln_b, scorer_w, enc, sAt, sBt);
  adam_kernel<<<B / 4, 256, 0, stream>>>(seqs, enc, sAt, sBt,
                                         mlp_w1, mlp_b1, mlp_w2, mlp_b2,
                                         out_w, out_b, (float*)d_out);
}